// Round 6
// baseline (245.075 us; speedup 1.0000x reference)
//
#include <hip/hip_runtime.h>
#include <math.h>

#define N 4096
#define NREL 5
#define NCH 2
#define NEDGE 131072
#define THRESH 0.05f
#define FSCALE 268435456.0f          // 2^28 fixed point for adjacency entries
#define INV_FSCALE_F (1.0f/268435456.0f)
#define INV_P56 (1.0/72057594037927936.0)   // 2^-56 (double, exact)
#define ROWCAP 256                   // per-row capacity: Poisson(160), +7.6 sigma
#define ROWS2 ((size_t)N * ROWCAP)   // entries per channel array

#define THRQ   13421773              // 0.05f == 13421773 / 2^28 EXACTLY (fits 24-bit mantissa)
#define MARGINQ 537                  // 2e-6 * 2^28; approx error <= ~25 units -> 20x cover
#define OVERQ  536870912u            // 2.0 * 2^28 overflow guard (empirical max H ~0.39)
#define WLCAP  4096

// ws layout in 4-byte elements:
//   CNT [0, 4096)        shared row counts (A1/A2 share structure)
//   WLC [4096]           worklist counter
//   WL  [4100, +4096)    worklist of flagged (m<<1|c)
//   E2  [E2_OFF ...)     int2 (col, q2) per channel, N*ROWCAP each
//   A1V [A1V_OFF ...)    int q1 per channel, parallel ordering
//   F   [F_OFF, +20)     softmax weights
#define CNT_OFF  ((size_t)0)
#define WLC_OFF  ((size_t)4096)
#define WL_OFF   ((size_t)4100)
#define E2_OFF   ((size_t)12288)                      // 16B-aligned base
#define A1V_OFF  (E2_OFF + (size_t)NCH * ROWS2 * 2)
#define F_OFF    (A1V_OFF + (size_t)NCH * ROWS2)

__global__ void softmax_kernel(const float* __restrict__ w1,
                               const float* __restrict__ w2,
                               float* __restrict__ F,
                               float* __restrict__ out_tail) {
    int c = threadIdx.x;
    if (c < 2 * NCH) {
        const float* w = (c < NCH) ? w1 : w2;
        int row = c % NCH;
        int base = (c < NCH) ? 0 : NCH * NREL;
        float m = -1e30f;
        for (int r = 0; r < NREL; ++r) m = fmaxf(m, w[row * NREL + r]);
        float e[NREL];
        float s = 0.f;
        for (int r = 0; r < NREL; ++r) { e[r] = expf(w[row * NREL + r] - m); s += e[r]; }
        float inv = 1.0f / s;
        for (int r = 0; r < NREL; ++r) {
            float f = e[r] * inv;
            F[base + row * NREL + r] = f;
            out_tail[base + row * NREL + r] = f;
        }
    }
}

// Append edges to per-row CSR (full 4096-wide columns). Duplicates unmerged
// (distributive integer accumulation == dense coalescing, bit-exact); entry
// order racy but consumers are order-independent integer sums.
__global__ void scatter_csr(const int* __restrict__ ei,
                            const float* __restrict__ ev,
                            const float* __restrict__ F,
                            int* __restrict__ CNT,
                            int2* __restrict__ E2,
                            int* __restrict__ A1V) {
    int t = blockIdx.x * blockDim.x + threadIdx.x;
    if (t >= NREL * NEDGE) return;
    int r = t / NEDGE;
    int e = t - r * NEDGE;
    int i = ei[(size_t)(r * 2 + 0) * NEDGE + e];
    int j = ei[(size_t)(r * 2 + 1) * NEDGE + e];
    float v = ev[(size_t)r * NEDGE + e];
    int pos = atomicAdd(&CNT[i], 1);
    if (pos < ROWCAP) {
        size_t idx = (size_t)i * ROWCAP + pos;
        int q1a = __float2int_rn(F[0 * NREL + r] * v * FSCALE);
        int q1b = __float2int_rn(F[1 * NREL + r] * v * FSCALE);
        int q2a = __float2int_rn(F[NCH * NREL + 0 * NREL + r] * v * FSCALE);
        int q2b = __float2int_rn(F[NCH * NREL + 1 * NREL + r] * v * FSCALE);
        E2[idx]          = make_int2(j, q2a);
        E2[ROWS2 + idx]  = make_int2(j, q2b);
        A1V[idx]         = q1a;
        A1V[ROWS2 + idx] = q1b;
    }
}

// Pass 1: u32 approximate accumulation (products rounded to 2^-28), full-width
// rows, one block per (m, c). Flags blocks with any cell near the 0.05 cut.
__launch_bounds__(256, 8)
__global__ void spgemm_approx(const int* __restrict__ CNT,
                              const int2* __restrict__ E2,
                              const int* __restrict__ A1V,
                              float* __restrict__ out,
                              int* __restrict__ WLC,
                              int* __restrict__ WL) {
    __shared__ unsigned int acc[N];     // 16KB
    __shared__ int kKC[ROWCAP];         // k | (cnt << 12)
    __shared__ int kA [ROWCAP];
    __shared__ int blkflag;
    const int m = blockIdx.x;
    const int c = blockIdx.y;
    const int2* __restrict__ e2 = E2  + (size_t)c * ROWS2;
    const int*  __restrict__ a1 = A1V + (size_t)c * ROWS2;

    for (int i = threadIdx.x; i < N; i += 256) acc[i] = 0u;
    if (threadIdx.x == 0) blkflag = 0;

    int nk = min(CNT[m], ROWCAP);
    for (int i = threadIdx.x; i < nk; i += 256) {
        size_t idx = (size_t)m * ROWCAP + i;
        int k = e2[idx].x;
        int cnt = min(CNT[k], ROWCAP);
        kKC[i] = k | (cnt << 12);
        kA[i]  = a1[idx];
    }
    __syncthreads();

    const int slot = threadIdx.x >> 5;
    const int lane = threadIdx.x & 31;
    const char* __restrict__ base = (const char*)e2;

    for (int ki = slot; ki < nk; ki += 16) {
        int kcA  = kKC[ki];
        int cntA = kcA >> 12;
        long long aA = (long long)kA[ki];
        const int4* __restrict__ rowA =
            (const int4*)(base + (unsigned)((kcA & 0xFFF) * (ROWCAP * 8)));

        int kiB = ki + 8;
        bool hasB = kiB < nk;
        int kcB  = hasB ? kKC[kiB] : 0;
        int cntB = hasB ? (kcB >> 12) : 0;
        long long aB = hasB ? (long long)kA[kiB] : 0;
        const int4* __restrict__ rowB =
            (const int4*)(base + (unsigned)((kcB & 0xFFF) * (ROWCAP * 8)));

        int PA = (cntA + 1) >> 1;
        int PB = (cntB + 1) >> 1;
        int P  = (PA > PB) ? PA : PB;
        for (int p = lane; p < P; p += 32) {
            int4 qa, qb;
            bool vA = p < PA, vB = p < PB;
            if (vA) qa = rowA[p];
            if (vB) qb = rowB[p];
            if (vA) {
                atomicAdd(&acc[qa.x],
                          (unsigned)((aA * (long long)qa.y + (1LL << 27)) >> 28));
                if (2 * p + 1 < cntA)
                    atomicAdd(&acc[qa.z],
                              (unsigned)((aA * (long long)qa.w + (1LL << 27)) >> 28));
            }
            if (vB) {
                atomicAdd(&acc[qb.x],
                          (unsigned)((aB * (long long)qb.y + (1LL << 27)) >> 28));
                if (2 * p + 1 < cntB)
                    atomicAdd(&acc[qb.z],
                              (unsigned)((aB * (long long)qb.w + (1LL << 27)) >> 28));
            }
        }
    }
    __syncthreads();

    // epilogue: convert, threshold, store; flag near-boundary / overflow cells
    float* orow = out + (size_t)c * N * N + (size_t)m * N;
    bool myflag = false;
    for (int t = threadIdx.x; t < N / 4; t += 256) {
        uint4 q = *(const uint4*)&acc[t * 4];
        unsigned vals[4] = {q.x, q.y, q.z, q.w};
        float4 hv;
        float* hp = (float*)&hv;
#pragma unroll
        for (int u = 0; u < 4; ++u) {
            unsigned v = vals[u];
            int d = (int)v - THRQ;
            myflag |= (d <= MARGINQ && d >= -MARGINQ) || (v >= OVERQ);
            float x = (float)v * INV_FSCALE_F;
            hp[u] = (x > THRESH) ? x : 0.f;
        }
        *(float4*)&orow[t * 4] = hv;
    }
    if (myflag) atomicOr(&blkflag, 1);
    __syncthreads();
    if (threadIdx.x == 0 && blkflag) {
        int pos = atomicAdd(WLC, 1);
        if (pos < WLCAP) WL[pos] = (m << 1) | c;
    }
}

// Pass 2: exact u64 recompute of flagged rows (bit-identical to the proven
// round-5 math), overwriting the approximate output.
__launch_bounds__(256, 4)
__global__ void spgemm_exact(const int* __restrict__ CNT,
                             const int2* __restrict__ E2,
                             const int* __restrict__ A1V,
                             float* __restrict__ out,
                             const int* __restrict__ WLC,
                             const int* __restrict__ WL) {
    int nwl = min(*WLC, WLCAP);
    if ((int)blockIdx.x >= nwl) return;
    int wl = WL[blockIdx.x];
    int m = wl >> 1;
    int c = wl & 1;

    __shared__ unsigned long long acc[N];   // 32KB
    __shared__ int kKC[ROWCAP];
    __shared__ int kA [ROWCAP];
    const int2* __restrict__ e2 = E2  + (size_t)c * ROWS2;
    const int*  __restrict__ a1 = A1V + (size_t)c * ROWS2;

    for (int i = threadIdx.x; i < N; i += 256) acc[i] = 0ULL;

    int nk = min(CNT[m], ROWCAP);
    for (int i = threadIdx.x; i < nk; i += 256) {
        size_t idx = (size_t)m * ROWCAP + i;
        int k = e2[idx].x;
        int cnt = min(CNT[k], ROWCAP);
        kKC[i] = k | (cnt << 12);
        kA[i]  = a1[idx];
    }
    __syncthreads();

    const int slot = threadIdx.x >> 5;
    const int lane = threadIdx.x & 31;
    const char* __restrict__ base = (const char*)e2;

    for (int ki = slot; ki < nk; ki += 16) {
        int kcA  = kKC[ki];
        int cntA = kcA >> 12;
        long long aA = (long long)kA[ki];
        const int4* __restrict__ rowA =
            (const int4*)(base + (unsigned)((kcA & 0xFFF) * (ROWCAP * 8)));

        int kiB = ki + 8;
        bool hasB = kiB < nk;
        int kcB  = hasB ? kKC[kiB] : 0;
        int cntB = hasB ? (kcB >> 12) : 0;
        long long aB = hasB ? (long long)kA[kiB] : 0;
        const int4* __restrict__ rowB =
            (const int4*)(base + (unsigned)((kcB & 0xFFF) * (ROWCAP * 8)));

        int PA = (cntA + 1) >> 1;
        int PB = (cntB + 1) >> 1;
        int P  = (PA > PB) ? PA : PB;
        for (int p = lane; p < P; p += 32) {
            int4 qa, qb;
            bool vA = p < PA, vB = p < PB;
            if (vA) qa = rowA[p];
            if (vB) qb = rowB[p];
            if (vA) {
                atomicAdd(&acc[qa.x], (unsigned long long)(aA * (long long)qa.y));
                if (2 * p + 1 < cntA)
                    atomicAdd(&acc[qa.z], (unsigned long long)(aA * (long long)qa.w));
            }
            if (vB) {
                atomicAdd(&acc[qb.x], (unsigned long long)(aB * (long long)qb.y));
                if (2 * p + 1 < cntB)
                    atomicAdd(&acc[qb.z], (unsigned long long)(aB * (long long)qb.w));
            }
        }
    }
    __syncthreads();

    float* orow = out + (size_t)c * N * N + (size_t)m * N;
    for (int t = threadIdx.x; t < N / 4; t += 256) {
        float4 hv;
        float* hp = (float*)&hv;
#pragma unroll
        for (int u = 0; u < 4; ++u) {
            double d = (double)(long long)acc[t * 4 + u] * INV_P56;
            float f = (float)d;
            hp[u] = (f > THRESH) ? f : 0.f;
        }
        *(float4*)&orow[t * 4] = hv;
    }
}

extern "C" void kernel_launch(void* const* d_in, const int* in_sizes, int n_in,
                              void* d_out, int out_size, void* d_ws, size_t ws_size,
                              hipStream_t stream) {
    const int*   ei = (const int*)d_in[0];     // [5, 2, 131072]
    const float* ev = (const float*)d_in[1];   // [5, 131072]
    const float* w1 = (const float*)d_in[2];   // [2, 5]
    const float* w2 = (const float*)d_in[3];   // [2, 5]
    float* out = (float*)d_out;                // H (2*N*N) then F1(10), F2(10)

    int*   wsI = (int*)d_ws;
    int*   CNT = wsI + CNT_OFF;
    int*   WLC = wsI + WLC_OFF;
    int*   WL  = wsI + WL_OFF;
    int2*  E2  = (int2*)(wsI + E2_OFF);
    int*   A1V = wsI + A1V_OFF;
    float* F   = (float*)(wsI + F_OFF);

    float* out_tail = out + (size_t)NCH * N * N;
    softmax_kernel<<<1, 64, 0, stream>>>(w1, w2, F, out_tail);

    // zero CNT (4096) + WLC (1); WL content is governed by WLC
    hipMemsetAsync(wsI, 0, (size_t)4097 * sizeof(int), stream);

    int total_edges = NREL * NEDGE;
    scatter_csr<<<(total_edges + 255) / 256, 256, 0, stream>>>(ei, ev, F, CNT, E2, A1V);

    spgemm_approx<<<dim3(N, NCH), 256, 0, stream>>>(CNT, E2, A1V, out, WLC, WL);
    spgemm_exact<<<WLCAP, 256, 0, stream>>>(CNT, E2, A1V, out, WLC, WL);
}

// Round 7
// 183.655 us; speedup vs baseline: 1.3344x; 1.3344x over previous
//
#include <hip/hip_runtime.h>
#include <math.h>

#define N 4096
#define NREL 5
#define NCH 2
#define NEDGE 131072
#define THRESH 0.05f
#define FSCALE 268435456.0f          // 2^28 fixed point for adjacency entries
#define INV_FSCALE_F (1.0f/268435456.0f)
#define INV_P56 (1.0/72057594037927936.0)   // 2^-56 (double, exact)
#define ROWCAP 192                   // per (row, col-half) capacity: Poisson(80), +12.5 sigma
#define KCAP   320                   // klist capacity (full row): Poisson(160), +12.7 sigma

#define THRQ    13421773             // 0.05f == 13421773 / 2^28 EXACTLY
#define MARGINQ 64                   // 2.4e-7 band; approx error <= ~15 units -> 4x cover
#define OVERQ   536870912u           // H >= 2.0 per half -> exact recompute (wrap needs H>=16)
#define WLCAP   2048

// ws layout in 4-byte elements:
//   CNT [0, 2N)          per (row, half) counts (A1/A2/channels share structure)
//   WLC [2N]             worklist counter
//   WL  [2N+1, +WLCAP)   flagged (m<<2 | h<<1 | c)
//   E2  [E2_OFF ...)     int4 (local col, q2_c0, q2_c1, pad) per entry
//   A1V [A1V_OFF ...)    int2 (q1_c0, q1_c1) parallel ordering
//   F   [F_OFF, +20)     softmax weights
#define CNT_OFF  ((size_t)0)
#define WLC_OFF  ((size_t)(2 * N))
#define WL_OFF   ((size_t)(2 * N + 1))
#define E2_OFF   ((size_t)12288)                       // 16B-aligned
#define E2_SZ    ((size_t)N * 2 * ROWCAP * 4)
#define A1V_OFF  (E2_OFF + E2_SZ)
#define F_OFF    (A1V_OFF + (size_t)N * 2 * ROWCAP * 2)

__global__ void softmax_kernel(const float* __restrict__ w1,
                               const float* __restrict__ w2,
                               float* __restrict__ F,
                               float* __restrict__ out_tail) {
    int c = threadIdx.x;
    if (c < 2 * NCH) {
        const float* w = (c < NCH) ? w1 : w2;
        int row = c % NCH;
        int base = (c < NCH) ? 0 : NCH * NREL;
        float m = -1e30f;
        for (int r = 0; r < NREL; ++r) m = fmaxf(m, w[row * NREL + r]);
        float e[NREL];
        float s = 0.f;
        for (int r = 0; r < NREL; ++r) { e[r] = expf(w[row * NREL + r] - m); s += e[r]; }
        float inv = 1.0f / s;
        for (int r = 0; r < NREL; ++r) {
            float f = e[r] * inv;
            F[base + row * NREL + r] = f;
            out_tail[base + row * NREL + r] = f;
        }
    }
}

// Append edges to bucketed CSR; both channels' values packed per entry.
// Duplicates unmerged (distributive integer accumulation == dense coalescing);
// entry order racy but consumers are order-independent integer sums.
__global__ void scatter_csr(const int* __restrict__ ei,
                            const float* __restrict__ ev,
                            const float* __restrict__ F,
                            int* __restrict__ CNT,
                            int4* __restrict__ E2,
                            int2* __restrict__ A1V) {
    int t = blockIdx.x * blockDim.x + threadIdx.x;
    if (t >= NREL * NEDGE) return;
    int r = t / NEDGE;
    int e = t - r * NEDGE;
    int i = ei[(size_t)(r * 2 + 0) * NEDGE + e];
    int j = ei[(size_t)(r * 2 + 1) * NEDGE + e];
    float v = ev[(size_t)r * NEDGE + e];
    int h  = j >> 11;
    int jl = j & 2047;
    int pos = atomicAdd(&CNT[i * 2 + h], 1);
    if (pos < ROWCAP) {
        size_t idx = ((size_t)i * 2 + h) * ROWCAP + pos;
        // per-edge quantization identical to the proven round-1/3/5 kernels
        int q1a = __float2int_rn(F[0 * NREL + r] * v * FSCALE);
        int q1b = __float2int_rn(F[1 * NREL + r] * v * FSCALE);
        int q2a = __float2int_rn(F[NCH * NREL + 0 * NREL + r] * v * FSCALE);
        int q2b = __float2int_rn(F[NCH * NREL + 1 * NREL + r] * v * FSCALE);
        E2[idx]  = make_int4(jl, q2a, q2b, 0);
        A1V[idx] = make_int2(q1a, q1b);
    }
}

// Pass 1: both channels at once. Products rounded to 2^-28 u32; channel 0 in
// the low word, channel 1 in the high word of ONE ds_add_u64 (no carry cross
// while each half-sum < 2^32 <=> H < 16; data max ~0.39, flagged at 2.0).
// One block per (m, h). Flags near-cut / overflow cells per channel.
__launch_bounds__(256, 8)
__global__ void spgemm_approx(const int* __restrict__ CNT,
                              const int4* __restrict__ E2,
                              const int2* __restrict__ A1V,
                              float* __restrict__ out,
                              int* __restrict__ WLC,
                              int* __restrict__ WL) {
    __shared__ unsigned long long acc[2048];   // 16KB: lo=c0, hi=c1
    __shared__ int2 kA[KCAP];                  // (q1_c0, q1_c1)
    __shared__ unsigned short kK[KCAP];        // k
    __shared__ unsigned char  kCt[KCAP];       // inner row count (<=192)
    __shared__ int blkflag;
    const int m = blockIdx.x;
    const int h = blockIdx.y;

    for (int i = threadIdx.x; i < 2048; i += 256) acc[i] = 0ULL;
    if (threadIdx.x == 0) blkflag = 0;

    int nk0 = min(CNT[m * 2 + 0], ROWCAP);
    int nk1 = min(CNT[m * 2 + 1], ROWCAP);
    int nk = min(nk0 + nk1, KCAP);
    for (int i = threadIdx.x; i < nk; i += 256) {
        int b  = (i >= nk0) ? 1 : 0;
        int ii = i - (b ? nk0 : 0);
        size_t idx = ((size_t)m * 2 + b) * ROWCAP + ii;
        int k = E2[idx].x + (b << 11);
        kK[i]  = (unsigned short)k;
        kCt[i] = (unsigned char)min(CNT[k * 2 + h], ROWCAP);
        kA[i]  = A1V[idx];
    }
    __syncthreads();

    const int slot = threadIdx.x >> 5;
    const int lane = threadIdx.x & 31;
    const char* __restrict__ base = (const char*)E2;

    for (int ki = slot; ki < nk; ki += 16) {
        int cntA = kCt[ki];
        int2 aA = kA[ki];
        const int4* __restrict__ rowA = (const int4*)
            (base + (unsigned)(((int)kK[ki] * 2 + h) * (ROWCAP * 16)));

        int kiB = ki + 8;
        bool hasB = kiB < nk;
        int cntB = hasB ? kCt[kiB] : 0;
        int2 aB = hasB ? kA[kiB] : make_int2(0, 0);
        const int4* __restrict__ rowB = (const int4*)
            (base + (unsigned)((((int)(hasB ? kK[kiB] : 0)) * 2 + h) * (ROWCAP * 16)));

        int P = (cntA > cntB) ? cntA : cntB;
        for (int p = lane; p < P; p += 32) {
            int4 qa, qb;
            bool vA = p < cntA, vB = p < cntB;
            if (vA) qa = rowA[p];
            if (vB) qb = rowB[p];
            if (vA) {
                unsigned pa = (unsigned)(((long long)aA.x * qa.y + (1LL << 27)) >> 28);
                unsigned pb = (unsigned)(((long long)aA.y * qa.z + (1LL << 27)) >> 28);
                atomicAdd(&acc[qa.x],
                          (unsigned long long)pa | ((unsigned long long)pb << 32));
            }
            if (vB) {
                unsigned pa = (unsigned)(((long long)aB.x * qb.y + (1LL << 27)) >> 28);
                unsigned pb = (unsigned)(((long long)aB.y * qb.z + (1LL << 27)) >> 28);
                atomicAdd(&acc[qb.x],
                          (unsigned long long)pa | ((unsigned long long)pb << 32));
            }
        }
    }
    __syncthreads();

    // epilogue: unpack halves, convert, threshold, store both channels;
    // flag near-boundary / overflow per channel.
    float* orow0 = out + (size_t)0 * N * N + (size_t)m * N + ((size_t)h << 11);
    float* orow1 = out + (size_t)1 * N * N + (size_t)m * N + ((size_t)h << 11);
    bool f0 = false, f1 = false;
    for (int t = threadIdx.x; t < 512; t += 256) {
        float4 h0, h1;
        float* p0 = (float*)&h0;
        float* p1 = (float*)&h1;
#pragma unroll
        for (int u = 0; u < 4; ++u) {
            unsigned long long v = acc[t * 4 + u];
            unsigned lo = (unsigned)v;
            unsigned hi = (unsigned)(v >> 32);
            int d0 = (int)lo - THRQ;
            int d1 = (int)hi - THRQ;
            f0 |= (d0 <= MARGINQ && d0 >= -MARGINQ) || (lo >= OVERQ);
            f1 |= (d1 <= MARGINQ && d1 >= -MARGINQ) || (hi >= OVERQ);
            float x0 = (float)lo * INV_FSCALE_F;
            float x1 = (float)hi * INV_FSCALE_F;
            p0[u] = (x0 > THRESH) ? x0 : 0.f;
            p1[u] = (x1 > THRESH) ? x1 : 0.f;
        }
        *(float4*)&orow0[t * 4] = h0;
        *(float4*)&orow1[t * 4] = h1;
    }
    if (f0) atomicOr(&blkflag, 1);
    if (f1) atomicOr(&blkflag, 2);
    __syncthreads();
    if (threadIdx.x == 0 && blkflag) {
        if (blkflag & 1) {
            int pos = atomicAdd(WLC, 1);
            if (pos < WLCAP) WL[pos] = (m << 2) | (h << 1) | 0;
        }
        if (blkflag & 2) {
            int pos = atomicAdd(WLC, 1);
            if (pos < WLCAP) WL[pos] = (m << 2) | (h << 1) | 1;
        }
    }
}

// Pass 2: exact u64 recompute of flagged (m, h, c) — bit-identical to the
// proven round-5 math — overwriting the approximate output.
__launch_bounds__(256, 8)
__global__ void spgemm_exact(const int* __restrict__ CNT,
                             const int4* __restrict__ E2,
                             const int2* __restrict__ A1V,
                             float* __restrict__ out,
                             const int* __restrict__ WLC,
                             const int* __restrict__ WL) {
    int nwl = min(*WLC, WLCAP);
    if ((int)blockIdx.x >= nwl) return;
    int wl = WL[blockIdx.x];
    int m = wl >> 2;
    int h = (wl >> 1) & 1;
    int c = wl & 1;

    __shared__ unsigned long long acc[2048];   // 16KB exact int64
    __shared__ int kAc[KCAP];
    __shared__ unsigned short kK[KCAP];
    __shared__ unsigned char  kCt[KCAP];

    for (int i = threadIdx.x; i < 2048; i += 256) acc[i] = 0ULL;

    int nk0 = min(CNT[m * 2 + 0], ROWCAP);
    int nk1 = min(CNT[m * 2 + 1], ROWCAP);
    int nk = min(nk0 + nk1, KCAP);
    for (int i = threadIdx.x; i < nk; i += 256) {
        int b  = (i >= nk0) ? 1 : 0;
        int ii = i - (b ? nk0 : 0);
        size_t idx = ((size_t)m * 2 + b) * ROWCAP + ii;
        int k = E2[idx].x + (b << 11);
        kK[i]  = (unsigned short)k;
        kCt[i] = (unsigned char)min(CNT[k * 2 + h], ROWCAP);
        int2 a = A1V[idx];
        kAc[i] = c ? a.y : a.x;
    }
    __syncthreads();

    const int slot = threadIdx.x >> 5;
    const int lane = threadIdx.x & 31;
    const char* __restrict__ base = (const char*)E2;

    for (int ki = slot; ki < nk; ki += 16) {
        int cntA = kCt[ki];
        long long aA = (long long)kAc[ki];
        const int4* __restrict__ rowA = (const int4*)
            (base + (unsigned)(((int)kK[ki] * 2 + h) * (ROWCAP * 16)));

        int kiB = ki + 8;
        bool hasB = kiB < nk;
        int cntB = hasB ? kCt[kiB] : 0;
        long long aB = hasB ? (long long)kAc[kiB] : 0;
        const int4* __restrict__ rowB = (const int4*)
            (base + (unsigned)((((int)(hasB ? kK[kiB] : 0)) * 2 + h) * (ROWCAP * 16)));

        int P = (cntA > cntB) ? cntA : cntB;
        for (int p = lane; p < P; p += 32) {
            int4 qa, qb;
            bool vA = p < cntA, vB = p < cntB;
            if (vA) qa = rowA[p];
            if (vB) qb = rowB[p];
            if (vA) {
                int q2 = c ? qa.z : qa.y;
                atomicAdd(&acc[qa.x], (unsigned long long)(aA * (long long)q2));
            }
            if (vB) {
                int q2 = c ? qb.z : qb.y;
                atomicAdd(&acc[qb.x], (unsigned long long)(aB * (long long)q2));
            }
        }
    }
    __syncthreads();

    float* orow = out + (size_t)c * N * N + (size_t)m * N + ((size_t)h << 11);
    for (int t = threadIdx.x; t < 512; t += 256) {
        float4 hv;
        float* hp = (float*)&hv;
#pragma unroll
        for (int u = 0; u < 4; ++u) {
            double d = (double)(long long)acc[t * 4 + u] * INV_P56;
            float f = (float)d;
            hp[u] = (f > THRESH) ? f : 0.f;
        }
        *(float4*)&orow[t * 4] = hv;
    }
}

extern "C" void kernel_launch(void* const* d_in, const int* in_sizes, int n_in,
                              void* d_out, int out_size, void* d_ws, size_t ws_size,
                              hipStream_t stream) {
    const int*   ei = (const int*)d_in[0];     // [5, 2, 131072]
    const float* ev = (const float*)d_in[1];   // [5, 131072]
    const float* w1 = (const float*)d_in[2];   // [2, 5]
    const float* w2 = (const float*)d_in[3];   // [2, 5]
    float* out = (float*)d_out;                // H (2*N*N) then F1(10), F2(10)

    int*   wsI = (int*)d_ws;
    int*   CNT = wsI + CNT_OFF;
    int*   WLC = wsI + WLC_OFF;
    int*   WL  = wsI + WL_OFF;
    int4*  E2  = (int4*)(wsI + E2_OFF);
    int2*  A1V = (int2*)(wsI + A1V_OFF);
    float* F   = (float*)(wsI + F_OFF);

    float* out_tail = out + (size_t)NCH * N * N;
    softmax_kernel<<<1, 64, 0, stream>>>(w1, w2, F, out_tail);

    // zero CNT (2N) + WLC (1); WL content governed by WLC
    hipMemsetAsync(wsI, 0, (size_t)(2 * N + 1) * sizeof(int), stream);

    int total_edges = NREL * NEDGE;
    scatter_csr<<<(total_edges + 255) / 256, 256, 0, stream>>>(ei, ev, F, CNT, E2, A1V);

    spgemm_approx<<<dim3(N, 2), 256, 0, stream>>>(CNT, E2, A1V, out, WLC, WL);
    spgemm_exact<<<WLCAP, 256, 0, stream>>>(CNT, E2, A1V, out, WLC, WL);
}

// Round 8
// 171.065 us; speedup vs baseline: 1.4326x; 1.0736x over previous
//
#include <hip/hip_runtime.h>
#include <math.h>

#define N 4096
#define NREL 5
#define NCH 2
#define NEDGE 131072
#define THRESH 0.05f
#define FSCALE 268435456.0f          // 2^28 fixed point for adjacency entries
#define INV_FSCALE_F (1.0f/268435456.0f)
#define INV_P56 (1.0/72057594037927936.0)   // 2^-56 (double, exact)
#define ROWCAP 192                   // per (row, col-half) capacity: Poisson(80), +12.5 sigma
#define KCAP   320                   // klist capacity (full row): Poisson(160), +12.7 sigma

#define THRQ    13421773             // 0.05f == 13421773 / 2^28 EXACTLY
#define MARGINQ 128                  // 4.8e-7 band; approx error <= ~1e-7 worst -> ~5x cover
#define OVERQ   536870912u           // H >= 2.0 per half -> exact recompute (wrap needs H>=16)
#define WLCAP   2048

// ws layout in 4-byte elements:
//   CNT [0, 2N)          per (row, half) counts (shared structure)
//   WLC [2N]             worklist counter
//   WL  [2N+1, +WLCAP)   flagged (m<<2 | h<<1 | c)
//   P8  [P8_OFF ...)     packed u64 approx entries: col | q2a'<<11 | q2b'<<37 (2^-25)
//   E2  [E2_OFF ...)     int4 (col, q2a, q2b, q1a) full-precision 2^-28 for exact pass
//   Q1B [Q1B_OFF ...)    int q1b (2^-28), parallel ordering
//   F   [F_OFF, +20)     softmax weights
#define CNT_OFF  ((size_t)0)
#define WLC_OFF  ((size_t)(2 * N))
#define WL_OFF   ((size_t)(2 * N + 1))
#define P8_OFF   ((size_t)16384)                     // 64KB-aligned base
#define NENT     ((size_t)N * 2 * ROWCAP)            // 1,572,864 entries
#define E2_OFF   (P8_OFF + NENT * 2)
#define Q1B_OFF  (E2_OFF + NENT * 4)
#define F_OFF    (Q1B_OFF + NENT)

__global__ void softmax_kernel(const float* __restrict__ w1,
                               const float* __restrict__ w2,
                               float* __restrict__ F,
                               float* __restrict__ out_tail) {
    int c = threadIdx.x;
    if (c < 2 * NCH) {
        const float* w = (c < NCH) ? w1 : w2;
        int row = c % NCH;
        int base = (c < NCH) ? 0 : NCH * NREL;
        float m = -1e30f;
        for (int r = 0; r < NREL; ++r) m = fmaxf(m, w[row * NREL + r]);
        float e[NREL];
        float s = 0.f;
        for (int r = 0; r < NREL; ++r) { e[r] = expf(w[row * NREL + r] - m); s += e[r]; }
        float inv = 1.0f / s;
        for (int r = 0; r < NREL; ++r) {
            float f = e[r] * inv;
            F[base + row * NREL + r] = f;
            out_tail[base + row * NREL + r] = f;
        }
    }
}

// Append edges to bucketed CSR. Duplicates unmerged (distributive integer
// accumulation == dense coalescing, bit-exact); entry order racy but all
// consumers are order-independent integer sums -> deterministic output.
__global__ void scatter_csr(const int* __restrict__ ei,
                            const float* __restrict__ ev,
                            const float* __restrict__ F,
                            int* __restrict__ CNT,
                            unsigned long long* __restrict__ P8,
                            int4* __restrict__ E2,
                            int* __restrict__ Q1B) {
    int t = blockIdx.x * blockDim.x + threadIdx.x;
    if (t >= NREL * NEDGE) return;
    int r = t / NEDGE;
    int e = t - r * NEDGE;
    int i = ei[(size_t)(r * 2 + 0) * NEDGE + e];
    int j = ei[(size_t)(r * 2 + 1) * NEDGE + e];
    float v = ev[(size_t)r * NEDGE + e];
    int h  = j >> 11;
    int jl = j & 2047;
    int pos = atomicAdd(&CNT[i * 2 + h], 1);
    if (pos < ROWCAP) {
        size_t idx = ((size_t)i * 2 + h) * ROWCAP + pos;
        // per-edge quantization identical to the proven round-1/3/5/7 kernels
        int q1a = __float2int_rn(F[0 * NREL + r] * v * FSCALE);
        int q1b = __float2int_rn(F[1 * NREL + r] * v * FSCALE);
        int q2a = __float2int_rn(F[NCH * NREL + 0 * NREL + r] * v * FSCALE);
        int q2b = __float2int_rn(F[NCH * NREL + 1 * NREL + r] * v * FSCALE);
        // packed approx entry at 2^-25 (q' = round(q/8); q <= 0.21*2^28 << 2^26*8)
        unsigned q2ap = ((unsigned)q2a + 4u) >> 3;
        unsigned q2bp = ((unsigned)q2b + 4u) >> 3;
        P8[idx] = (unsigned long long)jl
                | ((unsigned long long)q2ap << 11)
                | ((unsigned long long)q2bp << 37);
        E2[idx]  = make_int4(jl, q2a, q2b, q1a);
        Q1B[idx] = q1b;
    }
}

// Pass 1: both channels, packed 8B entries. Products at 2^-53 -> rounded >>25
// to the 2^-28 u32 accumulate; channel 0 low word, channel 1 high word of ONE
// ds_add_u64 (no carry cross while each half-sum < 2^32 <=> H < 16; flagged
// at 2.0). One block per (m, h). Flags near-cut / overflow cells per channel.
__launch_bounds__(256, 8)
__global__ void spgemm_approx(const int* __restrict__ CNT,
                              const unsigned long long* __restrict__ P8,
                              const int4* __restrict__ E2,
                              const int* __restrict__ Q1B,
                              float* __restrict__ out,
                              int* __restrict__ WLC,
                              int* __restrict__ WL) {
    __shared__ unsigned long long acc[2048];   // 16KB: lo=c0, hi=c1
    __shared__ int2 kA[KCAP];                  // (q1_c0, q1_c1)
    __shared__ unsigned short kK[KCAP];        // k
    __shared__ unsigned char  kCt[KCAP];       // inner row count (<=192)
    __shared__ int blkflag;
    const int m = blockIdx.x;
    const int h = blockIdx.y;

    for (int i = threadIdx.x; i < 2048; i += 256) acc[i] = 0ULL;
    if (threadIdx.x == 0) blkflag = 0;

    int nk0 = min(CNT[m * 2 + 0], ROWCAP);
    int nk1 = min(CNT[m * 2 + 1], ROWCAP);
    int nk = min(nk0 + nk1, KCAP);
    for (int i = threadIdx.x; i < nk; i += 256) {
        int b  = (i >= nk0) ? 1 : 0;
        int ii = i - (b ? nk0 : 0);
        size_t idx = ((size_t)m * 2 + b) * ROWCAP + ii;
        int4 e4 = E2[idx];
        int k = e4.x + (b << 11);
        kK[i]  = (unsigned short)k;
        kCt[i] = (unsigned char)min(CNT[k * 2 + h], ROWCAP);
        kA[i]  = make_int2(e4.w, Q1B[idx]);
    }
    __syncthreads();

    const int slot = threadIdx.x >> 5;
    const int lane = threadIdx.x & 31;

#define PROC(eu, ax, ay)                                                        \
    {                                                                           \
        unsigned col = (unsigned)(eu) & 2047u;                                  \
        unsigned qa  = (unsigned)((eu) >> 11) & 0x3FFFFFFu;                     \
        unsigned qb  = (unsigned)((eu) >> 37);                                  \
        unsigned ua = (unsigned)(((unsigned long long)(unsigned)(ax) * qa       \
                                  + (1ULL << 24)) >> 25);                       \
        unsigned ub = (unsigned)(((unsigned long long)(unsigned)(ay) * qb       \
                                  + (1ULL << 24)) >> 25);                       \
        atomicAdd(&acc[col],                                                    \
                  (unsigned long long)ua | ((unsigned long long)ub << 32));     \
    }

    for (int ki = slot; ki < nk; ki += 16) {
        int cntA = kCt[ki];
        int2 aA = kA[ki];
        const ulonglong2* __restrict__ rowA =
            (const ulonglong2*)(P8 + ((size_t)kK[ki] * 2 + h) * ROWCAP);

        int kiB = ki + 8;
        bool hasB = kiB < nk;
        int cntB = hasB ? kCt[kiB] : 0;
        int2 aB = hasB ? kA[kiB] : make_int2(0, 0);
        const ulonglong2* __restrict__ rowB =
            (const ulonglong2*)(P8 + ((size_t)(hasB ? kK[kiB] : 0) * 2 + h) * ROWCAP);

        int PA = (cntA + 1) >> 1;
        int PB = (cntB + 1) >> 1;
        int P  = (PA > PB) ? PA : PB;
        for (int p = lane; p < P; p += 32) {
            ulonglong2 ea, eb;
            bool vA = p < PA, vB = p < PB;
            if (vA) ea = rowA[p];
            if (vB) eb = rowB[p];
            if (vA) {
                PROC(ea.x, aA.x, aA.y);
                if (2 * p + 1 < cntA) PROC(ea.y, aA.x, aA.y);
            }
            if (vB) {
                PROC(eb.x, aB.x, aB.y);
                if (2 * p + 1 < cntB) PROC(eb.y, aB.x, aB.y);
            }
        }
    }
#undef PROC
    __syncthreads();

    // epilogue: unpack halves, convert, threshold, store both channels;
    // flag near-boundary / overflow per channel.
    float* orow0 = out + (size_t)0 * N * N + (size_t)m * N + ((size_t)h << 11);
    float* orow1 = out + (size_t)1 * N * N + (size_t)m * N + ((size_t)h << 11);
    bool f0 = false, f1 = false;
    for (int t = threadIdx.x; t < 512; t += 256) {
        float4 h0, h1;
        float* p0 = (float*)&h0;
        float* p1 = (float*)&h1;
#pragma unroll
        for (int u = 0; u < 4; ++u) {
            unsigned long long v = acc[t * 4 + u];
            unsigned lo = (unsigned)v;
            unsigned hi = (unsigned)(v >> 32);
            int d0 = (int)lo - THRQ;
            int d1 = (int)hi - THRQ;
            f0 |= (d0 <= MARGINQ && d0 >= -MARGINQ) || (lo >= OVERQ);
            f1 |= (d1 <= MARGINQ && d1 >= -MARGINQ) || (hi >= OVERQ);
            float x0 = (float)lo * INV_FSCALE_F;
            float x1 = (float)hi * INV_FSCALE_F;
            p0[u] = (x0 > THRESH) ? x0 : 0.f;
            p1[u] = (x1 > THRESH) ? x1 : 0.f;
        }
        *(float4*)&orow0[t * 4] = h0;
        *(float4*)&orow1[t * 4] = h1;
    }
    if (f0) atomicOr(&blkflag, 1);
    if (f1) atomicOr(&blkflag, 2);
    __syncthreads();
    if (threadIdx.x == 0 && blkflag) {
        if (blkflag & 1) {
            int pos = atomicAdd(WLC, 1);
            if (pos < WLCAP) WL[pos] = (m << 2) | (h << 1) | 0;
        }
        if (blkflag & 2) {
            int pos = atomicAdd(WLC, 1);
            if (pos < WLCAP) WL[pos] = (m << 2) | (h << 1) | 1;
        }
    }
}

// Pass 2: exact u64 recompute of flagged (m, h, c) — bit-identical to the
// proven round-5/7 math (full 2^-28 values from E2) — overwrites approx output.
__launch_bounds__(256, 8)
__global__ void spgemm_exact(const int* __restrict__ CNT,
                             const int4* __restrict__ E2,
                             const int* __restrict__ Q1B,
                             float* __restrict__ out,
                             const int* __restrict__ WLC,
                             const int* __restrict__ WL) {
    int nwl = min(*WLC, WLCAP);
    if ((int)blockIdx.x >= nwl) return;
    int wl = WL[blockIdx.x];
    int m = wl >> 2;
    int h = (wl >> 1) & 1;
    int c = wl & 1;

    __shared__ unsigned long long acc[2048];   // 16KB exact int64
    __shared__ int kAc[KCAP];
    __shared__ unsigned short kK[KCAP];
    __shared__ unsigned char  kCt[KCAP];

    for (int i = threadIdx.x; i < 2048; i += 256) acc[i] = 0ULL;

    int nk0 = min(CNT[m * 2 + 0], ROWCAP);
    int nk1 = min(CNT[m * 2 + 1], ROWCAP);
    int nk = min(nk0 + nk1, KCAP);
    for (int i = threadIdx.x; i < nk; i += 256) {
        int b  = (i >= nk0) ? 1 : 0;
        int ii = i - (b ? nk0 : 0);
        size_t idx = ((size_t)m * 2 + b) * ROWCAP + ii;
        int4 e4 = E2[idx];
        int k = e4.x + (b << 11);
        kK[i]  = (unsigned short)k;
        kCt[i] = (unsigned char)min(CNT[k * 2 + h], ROWCAP);
        kAc[i] = c ? Q1B[idx] : e4.w;
    }
    __syncthreads();

    const int slot = threadIdx.x >> 5;
    const int lane = threadIdx.x & 31;
    const char* __restrict__ base = (const char*)E2;

    for (int ki = slot; ki < nk; ki += 16) {
        int cntA = kCt[ki];
        long long aA = (long long)kAc[ki];
        const int4* __restrict__ rowA = (const int4*)
            (base + (unsigned)(((int)kK[ki] * 2 + h) * (ROWCAP * 16)));

        int kiB = ki + 8;
        bool hasB = kiB < nk;
        int cntB = hasB ? kCt[kiB] : 0;
        long long aB = hasB ? (long long)kAc[kiB] : 0;
        const int4* __restrict__ rowB = (const int4*)
            (base + (unsigned)((((int)(hasB ? kK[kiB] : 0)) * 2 + h) * (ROWCAP * 16)));

        int P = (cntA > cntB) ? cntA : cntB;
        for (int p = lane; p < P; p += 32) {
            int4 qa, qb;
            bool vA = p < cntA, vB = p < cntB;
            if (vA) qa = rowA[p];
            if (vB) qb = rowB[p];
            if (vA) {
                int q2 = c ? qa.z : qa.y;
                atomicAdd(&acc[qa.x], (unsigned long long)(aA * (long long)q2));
            }
            if (vB) {
                int q2 = c ? qb.z : qb.y;
                atomicAdd(&acc[qb.x], (unsigned long long)(aB * (long long)q2));
            }
        }
    }
    __syncthreads();

    float* orow = out + (size_t)c * N * N + (size_t)m * N + ((size_t)h << 11);
    for (int t = threadIdx.x; t < 512; t += 256) {
        float4 hv;
        float* hp = (float*)&hv;
#pragma unroll
        for (int u = 0; u < 4; ++u) {
            double d = (double)(long long)acc[t * 4 + u] * INV_P56;
            float f = (float)d;
            hp[u] = (f > THRESH) ? f : 0.f;
        }
        *(float4*)&orow[t * 4] = hv;
    }
}

extern "C" void kernel_launch(void* const* d_in, const int* in_sizes, int n_in,
                              void* d_out, int out_size, void* d_ws, size_t ws_size,
                              hipStream_t stream) {
    const int*   ei = (const int*)d_in[0];     // [5, 2, 131072]
    const float* ev = (const float*)d_in[1];   // [5, 131072]
    const float* w1 = (const float*)d_in[2];   // [2, 5]
    const float* w2 = (const float*)d_in[3];   // [2, 5]
    float* out = (float*)d_out;                // H (2*N*N) then F1(10), F2(10)

    int*   wsI = (int*)d_ws;
    int*   CNT = wsI + CNT_OFF;
    int*   WLC = wsI + WLC_OFF;
    int*   WL  = wsI + WL_OFF;
    unsigned long long* P8 = (unsigned long long*)(wsI + P8_OFF);
    int4*  E2  = (int4*)(wsI + E2_OFF);
    int*   Q1B = wsI + Q1B_OFF;
    float* F   = (float*)(wsI + F_OFF);

    float* out_tail = out + (size_t)NCH * N * N;
    softmax_kernel<<<1, 64, 0, stream>>>(w1, w2, F, out_tail);

    // zero CNT (2N) + WLC (1); WL content governed by WLC
    hipMemsetAsync(wsI, 0, (size_t)(2 * N + 1) * sizeof(int), stream);

    int total_edges = NREL * NEDGE;
    scatter_csr<<<(total_edges + 255) / 256, 256, 0, stream>>>(ei, ev, F, CNT, P8, E2, Q1B);

    spgemm_approx<<<dim3(N, 2), 256, 0, stream>>>(CNT, P8, E2, Q1B, out, WLC, WL);
    spgemm_exact<<<WLCAP, 256, 0, stream>>>(CNT, E2, Q1B, out, WLC, WL);
}

// Round 9
// 162.209 us; speedup vs baseline: 1.5109x; 1.0546x over previous
//
#include <hip/hip_runtime.h>
#include <math.h>

#define N 4096
#define NREL 5
#define NCH 2
#define NEDGE 131072
#define THRESH 0.05f
#define FSCALE 268435456.0f          // 2^28 fixed point for adjacency entries
#define INV_FSCALE_F (1.0f/268435456.0f)
#define INV_P56 (1.0/72057594037927936.0)   // 2^-56 (double, exact)
#define ROWCAP 192                   // per (row, col-half) capacity: Poisson(80), +12.5 sigma
#define KCAP   320                   // klist capacity (full row): Poisson(160), +12.7 sigma

#define THRQ    13421773             // 0.05f == 13421773 / 2^28 EXACTLY
#define MARGINQ 256                  // 9.5e-7 band; worst-case approx err ~120 units -> 2.1x cover
#define OVERQ   536870912u           // H >= 2.0 per half -> exact recompute (wrap needs H>=16)
#define WLCAP   2048

// ws layout in 4-byte elements:
//   CNT [0, 2N)          per (row, half) counts (shared structure)
//   WLC [2N]             worklist counter
//   WL  [2N+1, +WLCAP)   flagged (m<<2 | h<<1 | c)
//   P8  [P8_OFF ...)     packed 8B approx entries: lo32 = col | qa21<<11, hi32 = qb21 (2^-23)
//   E2  [E2_OFF ...)     int4 (col, q2a, q2b, q1a) full-precision 2^-28 for exact pass
//   Q1B [Q1B_OFF ...)    int q1b (2^-28), parallel ordering
//   F   [F_OFF, +20)     softmax weights
#define CNT_OFF  ((size_t)0)
#define WLC_OFF  ((size_t)(2 * N))
#define WL_OFF   ((size_t)(2 * N + 1))
#define P8_OFF   ((size_t)16384)                     // 64KB-aligned base
#define NENT     ((size_t)N * 2 * ROWCAP)            // 1,572,864 entries
#define E2_OFF   (P8_OFF + NENT * 2)
#define Q1B_OFF  (E2_OFF + NENT * 4)
#define F_OFF    (Q1B_OFF + NENT)

__global__ void softmax_kernel(const float* __restrict__ w1,
                               const float* __restrict__ w2,
                               float* __restrict__ F,
                               float* __restrict__ out_tail) {
    int c = threadIdx.x;
    if (c < 2 * NCH) {
        const float* w = (c < NCH) ? w1 : w2;
        int row = c % NCH;
        int base = (c < NCH) ? 0 : NCH * NREL;
        float m = -1e30f;
        for (int r = 0; r < NREL; ++r) m = fmaxf(m, w[row * NREL + r]);
        float e[NREL];
        float s = 0.f;
        for (int r = 0; r < NREL; ++r) { e[r] = expf(w[row * NREL + r] - m); s += e[r]; }
        float inv = 1.0f / s;
        for (int r = 0; r < NREL; ++r) {
            float f = e[r] * inv;
            F[base + row * NREL + r] = f;
            out_tail[base + row * NREL + r] = f;
        }
    }
}

// Append edges to bucketed CSR. Duplicates unmerged (distributive integer
// accumulation == dense coalescing, bit-exact); entry order racy but all
// consumers are order-independent integer sums -> deterministic output.
__global__ void scatter_csr(const int* __restrict__ ei,
                            const float* __restrict__ ev,
                            const float* __restrict__ F,
                            int* __restrict__ CNT,
                            unsigned long long* __restrict__ P8,
                            int4* __restrict__ E2,
                            int* __restrict__ Q1B) {
    int t = blockIdx.x * blockDim.x + threadIdx.x;
    if (t >= NREL * NEDGE) return;
    int r = t / NEDGE;
    int e = t - r * NEDGE;
    int i = ei[(size_t)(r * 2 + 0) * NEDGE + e];
    int j = ei[(size_t)(r * 2 + 1) * NEDGE + e];
    float v = ev[(size_t)r * NEDGE + e];
    int h  = j >> 11;
    int jl = j & 2047;
    int pos = atomicAdd(&CNT[i * 2 + h], 1);
    if (pos < ROWCAP) {
        size_t idx = ((size_t)i * 2 + h) * ROWCAP + pos;
        // per-edge quantization identical to the proven round-1/3/5/7 kernels
        int q1a = __float2int_rn(F[0 * NREL + r] * v * FSCALE);
        int q1b = __float2int_rn(F[1 * NREL + r] * v * FSCALE);
        int q2a = __float2int_rn(F[NCH * NREL + 0 * NREL + r] * v * FSCALE);
        int q2b = __float2int_rn(F[NCH * NREL + 1 * NREL + r] * v * FSCALE);
        // packed approx entry at 2^-23 (q' = round(q/32); q2 < 2^26 since F < 0.25
        // -> q' < 2^21, no straddle across the 32-bit word boundary)
        unsigned qa21 = ((unsigned)q2a + 16u) >> 5;
        unsigned qb21 = ((unsigned)q2b + 16u) >> 5;
        unsigned w0 = (unsigned)jl | (qa21 << 11);
        P8[idx] = (unsigned long long)w0 | ((unsigned long long)qb21 << 32);
        E2[idx]  = make_int4(jl, q2a, q2b, q1a);
        Q1B[idx] = q1b;
    }
}

// Pass 1: both channels, packed 8B non-straddling entries. One v_mad_u64_u32
// per channel (rounding folded), >>23 to the 2^-28 u32 accumulate; channel 0
// low word, channel 1 high word of ONE ds_add_u64 (no carry cross while each
// half-sum < 2^32 <=> H < 16; flagged at 2.0). One block per (m, h); 16
// single-stream 16-lane slots. Flags near-cut / overflow cells per channel.
__launch_bounds__(256, 8)
__global__ void spgemm_approx(const int* __restrict__ CNT,
                              const unsigned long long* __restrict__ P8,
                              const int4* __restrict__ E2,
                              const int* __restrict__ Q1B,
                              float* __restrict__ out,
                              int* __restrict__ WLC,
                              int* __restrict__ WL) {
    __shared__ unsigned long long acc[2048];   // 16KB: lo=c0, hi=c1
    __shared__ int2 kA[KCAP];                  // (q1_c0, q1_c1)
    __shared__ unsigned short kK[KCAP];        // k
    __shared__ unsigned char  kCt[KCAP];       // inner row count (<=192)
    __shared__ int blkflag;
    const int m = blockIdx.x;
    const int h = blockIdx.y;

    for (int i = threadIdx.x; i < 2048; i += 256) acc[i] = 0ULL;
    if (threadIdx.x == 0) blkflag = 0;

    int nk0 = min(CNT[m * 2 + 0], ROWCAP);
    int nk1 = min(CNT[m * 2 + 1], ROWCAP);
    int nk = min(nk0 + nk1, KCAP);
    for (int i = threadIdx.x; i < nk; i += 256) {
        int b  = (i >= nk0) ? 1 : 0;
        int ii = i - (b ? nk0 : 0);
        size_t idx = ((size_t)m * 2 + b) * ROWCAP + ii;
        int4 e4 = E2[idx];
        int k = e4.x + (b << 11);
        kK[i]  = (unsigned short)k;
        kCt[i] = (unsigned char)min(CNT[k * 2 + h], ROWCAP);
        kA[i]  = make_int2(e4.w, Q1B[idx]);
    }
    __syncthreads();

    const int slot = threadIdx.x >> 4;   // 16 slots
    const int lane = threadIdx.x & 15;   // 16 lanes

#define PROC(eu, a0, a1)                                                        \
    {                                                                           \
        unsigned w0  = (unsigned)(eu);                                          \
        unsigned w1  = (unsigned)((eu) >> 32);                                  \
        unsigned col = w0 & 2047u;                                              \
        unsigned qa  = w0 >> 11;                                                \
        unsigned long long pA =                                                 \
            (unsigned long long)(unsigned)(a0) * qa + (1u << 22);               \
        unsigned long long pB =                                                 \
            (unsigned long long)(unsigned)(a1) * w1 + (1u << 22);               \
        unsigned uA = (unsigned)(pA >> 23);                                     \
        unsigned uB = (unsigned)(pB >> 23);                                     \
        atomicAdd(&acc[col],                                                    \
                  (unsigned long long)uA | ((unsigned long long)uB << 32));     \
    }

    for (int ki = slot; ki < nk; ki += 16) {
        int cntA = kCt[ki];
        int2 aA = kA[ki];
        const ulonglong2* __restrict__ rowA =
            (const ulonglong2*)(P8 + ((size_t)kK[ki] * 2 + h) * ROWCAP);
        int PA = (cntA + 1) >> 1;
        for (int p = lane; p < PA; p += 16) {
            ulonglong2 e = rowA[p];
            PROC(e.x, aA.x, aA.y);
            if (2 * p + 1 < cntA) PROC(e.y, aA.x, aA.y);
        }
    }
#undef PROC
    __syncthreads();

    // epilogue: unpack halves, convert, threshold, store both channels;
    // flag near-boundary / overflow per channel.
    float* orow0 = out + (size_t)0 * N * N + (size_t)m * N + ((size_t)h << 11);
    float* orow1 = out + (size_t)1 * N * N + (size_t)m * N + ((size_t)h << 11);
    bool f0 = false, f1 = false;
    for (int t = threadIdx.x; t < 512; t += 256) {
        float4 h0, h1;
        float* p0 = (float*)&h0;
        float* p1 = (float*)&h1;
#pragma unroll
        for (int u = 0; u < 4; ++u) {
            unsigned long long v = acc[t * 4 + u];
            unsigned lo = (unsigned)v;
            unsigned hi = (unsigned)(v >> 32);
            int d0 = (int)lo - THRQ;
            int d1 = (int)hi - THRQ;
            f0 |= (d0 <= MARGINQ && d0 >= -MARGINQ) || (lo >= OVERQ);
            f1 |= (d1 <= MARGINQ && d1 >= -MARGINQ) || (hi >= OVERQ);
            float x0 = (float)lo * INV_FSCALE_F;
            float x1 = (float)hi * INV_FSCALE_F;
            p0[u] = (x0 > THRESH) ? x0 : 0.f;
            p1[u] = (x1 > THRESH) ? x1 : 0.f;
        }
        *(float4*)&orow0[t * 4] = h0;
        *(float4*)&orow1[t * 4] = h1;
    }
    if (f0) atomicOr(&blkflag, 1);
    if (f1) atomicOr(&blkflag, 2);
    __syncthreads();
    if (threadIdx.x == 0 && blkflag) {
        if (blkflag & 1) {
            int pos = atomicAdd(WLC, 1);
            if (pos < WLCAP) WL[pos] = (m << 2) | (h << 1) | 0;
        }
        if (blkflag & 2) {
            int pos = atomicAdd(WLC, 1);
            if (pos < WLCAP) WL[pos] = (m << 2) | (h << 1) | 1;
        }
    }
}

// Pass 2: exact u64 recompute of flagged (m, h, c) — bit-identical to the
// proven round-5/7 math (full 2^-28 values from E2) — overwrites approx output.
__launch_bounds__(256, 8)
__global__ void spgemm_exact(const int* __restrict__ CNT,
                             const int4* __restrict__ E2,
                             const int* __restrict__ Q1B,
                             float* __restrict__ out,
                             const int* __restrict__ WLC,
                             const int* __restrict__ WL) {
    int nwl = min(*WLC, WLCAP);
    if ((int)blockIdx.x >= nwl) return;
    int wl = WL[blockIdx.x];
    int m = wl >> 2;
    int h = (wl >> 1) & 1;
    int c = wl & 1;

    __shared__ unsigned long long acc[2048];   // 16KB exact int64
    __shared__ int kAc[KCAP];
    __shared__ unsigned short kK[KCAP];
    __shared__ unsigned char  kCt[KCAP];

    for (int i = threadIdx.x; i < 2048; i += 256) acc[i] = 0ULL;

    int nk0 = min(CNT[m * 2 + 0], ROWCAP);
    int nk1 = min(CNT[m * 2 + 1], ROWCAP);
    int nk = min(nk0 + nk1, KCAP);
    for (int i = threadIdx.x; i < nk; i += 256) {
        int b  = (i >= nk0) ? 1 : 0;
        int ii = i - (b ? nk0 : 0);
        size_t idx = ((size_t)m * 2 + b) * ROWCAP + ii;
        int4 e4 = E2[idx];
        int k = e4.x + (b << 11);
        kK[i]  = (unsigned short)k;
        kCt[i] = (unsigned char)min(CNT[k * 2 + h], ROWCAP);
        kAc[i] = c ? Q1B[idx] : e4.w;
    }
    __syncthreads();

    const int slot = threadIdx.x >> 5;
    const int lane = threadIdx.x & 31;
    const char* __restrict__ base = (const char*)E2;

    for (int ki = slot; ki < nk; ki += 16) {
        int cntA = kCt[ki];
        long long aA = (long long)kAc[ki];
        const int4* __restrict__ rowA = (const int4*)
            (base + (unsigned)(((int)kK[ki] * 2 + h) * (ROWCAP * 16)));

        int kiB = ki + 8;
        bool hasB = kiB < nk;
        int cntB = hasB ? kCt[kiB] : 0;
        long long aB = hasB ? (long long)kAc[kiB] : 0;
        const int4* __restrict__ rowB = (const int4*)
            (base + (unsigned)((((int)(hasB ? kK[kiB] : 0)) * 2 + h) * (ROWCAP * 16)));

        int P = (cntA > cntB) ? cntA : cntB;
        for (int p = lane; p < P; p += 32) {
            int4 qa, qb;
            bool vA = p < cntA, vB = p < cntB;
            if (vA) qa = rowA[p];
            if (vB) qb = rowB[p];
            if (vA) {
                int q2 = c ? qa.z : qa.y;
                atomicAdd(&acc[qa.x], (unsigned long long)(aA * (long long)q2));
            }
            if (vB) {
                int q2 = c ? qb.z : qb.y;
                atomicAdd(&acc[qb.x], (unsigned long long)(aB * (long long)q2));
            }
        }
    }
    __syncthreads();

    float* orow = out + (size_t)c * N * N + (size_t)m * N + ((size_t)h << 11);
    for (int t = threadIdx.x; t < 512; t += 256) {
        float4 hv;
        float* hp = (float*)&hv;
#pragma unroll
        for (int u = 0; u < 4; ++u) {
            double d = (double)(long long)acc[t * 4 + u] * INV_P56;
            float f = (float)d;
            hp[u] = (f > THRESH) ? f : 0.f;
        }
        *(float4*)&orow[t * 4] = hv;
    }
}

extern "C" void kernel_launch(void* const* d_in, const int* in_sizes, int n_in,
                              void* d_out, int out_size, void* d_ws, size_t ws_size,
                              hipStream_t stream) {
    const int*   ei = (const int*)d_in[0];     // [5, 2, 131072]
    const float* ev = (const float*)d_in[1];   // [5, 131072]
    const float* w1 = (const float*)d_in[2];   // [2, 5]
    const float* w2 = (const float*)d_in[3];   // [2, 5]
    float* out = (float*)d_out;                // H (2*N*N) then F1(10), F2(10)

    int*   wsI = (int*)d_ws;
    int*   CNT = wsI + CNT_OFF;
    int*   WLC = wsI + WLC_OFF;
    int*   WL  = wsI + WL_OFF;
    unsigned long long* P8 = (unsigned long long*)(wsI + P8_OFF);
    int4*  E2  = (int4*)(wsI + E2_OFF);
    int*   Q1B = wsI + Q1B_OFF;
    float* F   = (float*)(wsI + F_OFF);

    float* out_tail = out + (size_t)NCH * N * N;
    softmax_kernel<<<1, 64, 0, stream>>>(w1, w2, F, out_tail);

    // zero CNT (2N) + WLC (1); WL content governed by WLC
    hipMemsetAsync(wsI, 0, (size_t)(2 * N + 1) * sizeof(int), stream);

    int total_edges = NREL * NEDGE;
    scatter_csr<<<(total_edges + 255) / 256, 256, 0, stream>>>(ei, ev, F, CNT, P8, E2, Q1B);

    spgemm_approx<<<dim3(N, 2), 256, 0, stream>>>(CNT, P8, E2, Q1B, out, WLC, WL);
    spgemm_exact<<<WLCAP, 256, 0, stream>>>(CNT, E2, Q1B, out, WLC, WL);
}

// Round 11
// 158.143 us; speedup vs baseline: 1.5497x; 1.0257x over previous
//
#include <hip/hip_runtime.h>
#include <math.h>

#define N 4096
#define NREL 5
#define NCH 2
#define NEDGE 131072
#define THRESH 0.05f
#define FSCALE 268435456.0f          // 2^28 fixed point for adjacency entries
#define INV_P24F (1.0f/16777216.0f)  // 2^-24 (exact)
#define INV_P56 (1.0/72057594037927936.0)   // 2^-56 (double, exact)
#define ROWCAP 192                   // per (row, col-half) capacity: Poisson(80), +12.5 sigma
#define KCAP   320                   // klist capacity (full row): Poisson(160), +12.7 sigma

#define THRQ24  838860               // floor(0.05f * 2^24); cut acc > THRQ24 == x > 0.05f
#define MARGIN24 32                  // +-32 ulp @2^-24; worst-case err <= ~15 ulp -> 2.1x cover
#define OVERQ24 33554432u            // 2.0 * 2^24 per half -> exact recompute (wrap at 256)
#define WLCAP   16384                // = N*2*2 = ALL (m,h,c) blocks: drops impossible
#define Q2MASK  0x3FFFFFFu

// ws layout in 4-byte elements:
//   CNT [0, 2N)          per (row, half) counts (shared structure)
//   WLC [2N]             worklist counter
//   WL  [2N+1, +WLCAP)   flagged (m<<2 | h<<1 | c); capacity = all blocks
//   P8  [P8_OFF ...)     packed 8B entries: col | q2a<<11 | q2b<<38 (RAW 2^-28 ints)
//   A4  [A4_OFF ...)     int2 (q1a, q1b) raw 2^-28 ints, parallel ordering
//   F   [F_OFF, +20)     softmax weights
#define CNT_OFF  ((size_t)0)
#define WLC_OFF  ((size_t)(2 * N))
#define WL_OFF   ((size_t)(2 * N + 1))
#define P8_OFF   ((size_t)32768)                     // past WL end (24577), 128KB-aligned
#define NENT     ((size_t)N * 2 * ROWCAP)            // 1,572,864 entries
#define A4_OFF   (P8_OFF + NENT * 2)
#define F_OFF    (A4_OFF + NENT * 2)

// Fused: zero CNT+WLC (blocks 0..31) and compute softmaxes (block 32).
__global__ void init_kernel(const float* __restrict__ w1,
                            const float* __restrict__ w2,
                            float* __restrict__ F,
                            float* __restrict__ out_tail,
                            int* __restrict__ CNTZ) {
    int gid = blockIdx.x * 256 + threadIdx.x;
    if (gid < 2 * N + 1) CNTZ[gid] = 0;
    if (blockIdx.x == 32 && threadIdx.x < 2 * NCH) {
        int c = threadIdx.x;
        const float* w = (c < NCH) ? w1 : w2;
        int row = c % NCH;
        int base = (c < NCH) ? 0 : NCH * NREL;
        float m = -1e30f;
        for (int r = 0; r < NREL; ++r) m = fmaxf(m, w[row * NREL + r]);
        float e[NREL];
        float s = 0.f;
        for (int r = 0; r < NREL; ++r) { e[r] = expf(w[row * NREL + r] - m); s += e[r]; }
        float inv = 1.0f / s;
        for (int r = 0; r < NREL; ++r) {
            float f = e[r] * inv;
            F[base + row * NREL + r] = f;
            out_tail[base + row * NREL + r] = f;
        }
    }
}

// Append edges to bucketed CSR. Duplicates unmerged (distributive integer
// accumulation == dense coalescing, bit-exact); entry order racy but all
// consumers are order-independent integer sums -> deterministic output.
__global__ void scatter_csr(const int* __restrict__ ei,
                            const float* __restrict__ ev,
                            const float* __restrict__ F,
                            int* __restrict__ CNT,
                            unsigned long long* __restrict__ P8,
                            int2* __restrict__ A4) {
    int t = blockIdx.x * blockDim.x + threadIdx.x;
    if (t >= NREL * NEDGE) return;
    int r = t / NEDGE;
    int e = t - r * NEDGE;
    int i = ei[(size_t)(r * 2 + 0) * NEDGE + e];
    int j = ei[(size_t)(r * 2 + 1) * NEDGE + e];
    float v = ev[(size_t)r * NEDGE + e];
    int h  = j >> 11;
    int jl = j & 2047;
    int pos = atomicAdd(&CNT[i * 2 + h], 1);
    if (pos < ROWCAP) {
        size_t idx = ((size_t)i * 2 + h) * ROWCAP + pos;
        // per-edge quantization identical to the proven round-1/3/5/7 kernels
        unsigned q1a = (unsigned)__float2int_rn(F[0 * NREL + r] * v * FSCALE);
        unsigned q1b = (unsigned)__float2int_rn(F[1 * NREL + r] * v * FSCALE);
        unsigned q2a = (unsigned)__float2int_rn(F[NCH * NREL + 0 * NREL + r] * v * FSCALE);
        unsigned q2b = (unsigned)__float2int_rn(F[NCH * NREL + 1 * NREL + r] * v * FSCALE);
        // q2 < 2^26 given F ~ 0.2, v < 1 (clamp = pure safety, never hit)
        q2a = min(q2a, Q2MASK);
        q2b = min(q2b, Q2MASK);
        P8[idx] = (unsigned long long)(unsigned)jl
                | ((unsigned long long)q2a << 11)
                | ((unsigned long long)q2b << 38);
        A4[idx] = make_int2((int)q1a, (int)q1b);
    }
}

// Pass 1: both channels. Per entry: two v_mad_u64_u32(q1, q2, 2^31); the high
// 32 bits ARE the 2^-24-scale contributions (no shifts, no repack) -> one
// ds_add_u64 (c0 low word, c1 high word; no carry cross while each half < 2^32
// <=> H < 256; flagged at 2.0). One block per (m, h); 16 16-lane slots.
__launch_bounds__(256, 8)
__global__ void spgemm_approx(const int* __restrict__ CNT,
                              const unsigned long long* __restrict__ P8,
                              const int2* __restrict__ A4,
                              float* __restrict__ out,
                              int* __restrict__ WLC,
                              int* __restrict__ WL) {
    __shared__ unsigned long long acc[2048];   // 16KB: lo=c0, hi=c1
    __shared__ int2 kA[KCAP];                  // (q1_c0, q1_c1)
    __shared__ unsigned short kK[KCAP];        // k
    __shared__ unsigned char  kCt[KCAP];       // inner row count (<=192)
    __shared__ int blkflag;
    const int m = blockIdx.x;
    const int h = blockIdx.y;

    for (int i = threadIdx.x; i < 2048; i += 256) acc[i] = 0ULL;
    if (threadIdx.x == 0) blkflag = 0;

    int nk0 = min(CNT[m * 2 + 0], ROWCAP);
    int nk1 = min(CNT[m * 2 + 1], ROWCAP);
    int nk = min(nk0 + nk1, KCAP);
    for (int i = threadIdx.x; i < nk; i += 256) {
        int b  = (i >= nk0) ? 1 : 0;
        int ii = i - (b ? nk0 : 0);
        size_t idx = ((size_t)m * 2 + b) * ROWCAP + ii;
        int k = (int)(P8[idx] & 2047ULL) + (b << 11);
        kK[i]  = (unsigned short)k;
        kCt[i] = (unsigned char)min(CNT[k * 2 + h], ROWCAP);
        kA[i]  = A4[idx];
    }
    __syncthreads();

    const int slot = threadIdx.x >> 4;   // 16 slots
    const int lane = threadIdx.x & 15;   // 16 lanes

#define PROC(eu, a0, a1)                                                        \
    {                                                                           \
        unsigned col = (unsigned)(eu) & 2047u;                                  \
        unsigned qa  = (unsigned)((eu) >> 11) & Q2MASK;                         \
        unsigned qb  = (unsigned)((eu) >> 38);                                  \
        unsigned long long pA =                                                 \
            (unsigned long long)(unsigned)(a0) * qa + (1ULL << 31);             \
        unsigned long long pB =                                                 \
            (unsigned long long)(unsigned)(a1) * qb + (1ULL << 31);             \
        unsigned uA = (unsigned)(pA >> 32);                                     \
        unsigned uB = (unsigned)(pB >> 32);                                     \
        atomicAdd(&acc[col],                                                    \
                  (unsigned long long)uA | ((unsigned long long)uB << 32));     \
    }

    for (int ki = slot; ki < nk; ki += 16) {
        int cntA = kCt[ki];
        int2 aA = kA[ki];
        const ulonglong2* __restrict__ rowA =
            (const ulonglong2*)(P8 + ((size_t)kK[ki] * 2 + h) * ROWCAP);
        int PA = (cntA + 1) >> 1;
        for (int p = lane; p < PA; p += 16) {
            ulonglong2 e = rowA[p];
            PROC(e.x, aA.x, aA.y);
            if (2 * p + 1 < cntA) PROC(e.y, aA.x, aA.y);
        }
    }
#undef PROC
    __syncthreads();

    // epilogue: unpack halves, convert (exact: lo < 2^24 at scale 2^-24),
    // threshold, store both channels; flag near-boundary / overflow cells.
    float* orow0 = out + (size_t)0 * N * N + (size_t)m * N + ((size_t)h << 11);
    float* orow1 = out + (size_t)1 * N * N + (size_t)m * N + ((size_t)h << 11);
    bool f0 = false, f1 = false;
    for (int t = threadIdx.x; t < 512; t += 256) {
        float4 h0, h1;
        float* p0 = (float*)&h0;
        float* p1 = (float*)&h1;
#pragma unroll
        for (int u = 0; u < 4; ++u) {
            unsigned long long v = acc[t * 4 + u];
            unsigned lo = (unsigned)v;
            unsigned hi = (unsigned)(v >> 32);
            int d0 = (int)lo - THRQ24;
            int d1 = (int)hi - THRQ24;
            f0 |= (d0 <= MARGIN24 && d0 >= -MARGIN24) || (lo >= OVERQ24);
            f1 |= (d1 <= MARGIN24 && d1 >= -MARGIN24) || (hi >= OVERQ24);
            float x0 = (float)lo * INV_P24F;
            float x1 = (float)hi * INV_P24F;
            p0[u] = ((int)lo > THRQ24) ? x0 : 0.f;
            p1[u] = ((int)hi > THRQ24) ? x1 : 0.f;
        }
        *(float4*)&orow0[t * 4] = h0;
        *(float4*)&orow1[t * 4] = h1;
    }
    if (f0) atomicOr(&blkflag, 1);
    if (f1) atomicOr(&blkflag, 2);
    __syncthreads();
    if (threadIdx.x == 0 && blkflag) {
        // WLCAP == total block count -> pos can never reach WLCAP: no drops.
        if (blkflag & 1) {
            int pos = atomicAdd(WLC, 1);
            if (pos < WLCAP) WL[pos] = (m << 2) | (h << 1) | 0;
        }
        if (blkflag & 2) {
            int pos = atomicAdd(WLC, 1);
            if (pos < WLCAP) WL[pos] = (m << 2) | (h << 1) | 1;
        }
    }
}

// Pass 2: exact u64 recompute of flagged (m, h, c). P8 carries the RAW 2^-28
// q2 ints -> products q1*q2 and the u64 sum are bit-identical to the proven
// round-5/7 exact math. Overwrites the approximate output.
__launch_bounds__(256, 8)
__global__ void spgemm_exact(const int* __restrict__ CNT,
                             const unsigned long long* __restrict__ P8,
                             const int2* __restrict__ A4,
                             float* __restrict__ out,
                             const int* __restrict__ WLC,
                             const int* __restrict__ WL) {
    int nwl = min(*WLC, WLCAP);
    if ((int)blockIdx.x >= nwl) return;
    int wl = WL[blockIdx.x];
    int m = wl >> 2;
    int h = (wl >> 1) & 1;
    int c = wl & 1;

    __shared__ unsigned long long acc[2048];   // 16KB exact int64
    __shared__ unsigned kAc[KCAP];
    __shared__ unsigned short kK[KCAP];
    __shared__ unsigned char  kCt[KCAP];

    for (int i = threadIdx.x; i < 2048; i += 256) acc[i] = 0ULL;

    int nk0 = min(CNT[m * 2 + 0], ROWCAP);
    int nk1 = min(CNT[m * 2 + 1], ROWCAP);
    int nk = min(nk0 + nk1, KCAP);
    for (int i = threadIdx.x; i < nk; i += 256) {
        int b  = (i >= nk0) ? 1 : 0;
        int ii = i - (b ? nk0 : 0);
        size_t idx = ((size_t)m * 2 + b) * ROWCAP + ii;
        int k = (int)(P8[idx] & 2047ULL) + (b << 11);
        kK[i]  = (unsigned short)k;
        kCt[i] = (unsigned char)min(CNT[k * 2 + h], ROWCAP);
        int2 a = A4[idx];
        kAc[i] = (unsigned)(c ? a.y : a.x);
    }
    __syncthreads();

    const int slot = threadIdx.x >> 4;
    const int lane = threadIdx.x & 15;
    const int shift = c ? 38 : 11;

    for (int ki = slot; ki < nk; ki += 16) {
        int cnt = kCt[ki];
        unsigned long long a = (unsigned long long)kAc[ki];
        const unsigned long long* __restrict__ row =
            P8 + ((size_t)kK[ki] * 2 + h) * ROWCAP;
        for (int p = lane; p < cnt; p += 16) {
            unsigned long long e = row[p];
            unsigned col = (unsigned)e & 2047u;
            unsigned q2 = (unsigned)(e >> shift) & Q2MASK;
            atomicAdd(&acc[col], a * (unsigned long long)q2);
        }
    }
    __syncthreads();

    float* orow = out + (size_t)c * N * N + (size_t)m * N + ((size_t)h << 11);
    for (int t = threadIdx.x; t < 512; t += 256) {
        float4 hv;
        float* hp = (float*)&hv;
#pragma unroll
        for (int u = 0; u < 4; ++u) {
            double d = (double)(long long)acc[t * 4 + u] * INV_P56;
            float f = (float)d;
            hp[u] = (f > THRESH) ? f : 0.f;
        }
        *(float4*)&orow[t * 4] = hv;
    }
}

extern "C" void kernel_launch(void* const* d_in, const int* in_sizes, int n_in,
                              void* d_out, int out_size, void* d_ws, size_t ws_size,
                              hipStream_t stream) {
    const int*   ei = (const int*)d_in[0];     // [5, 2, 131072]
    const float* ev = (const float*)d_in[1];   // [5, 131072]
    const float* w1 = (const float*)d_in[2];   // [2, 5]
    const float* w2 = (const float*)d_in[3];   // [2, 5]
    float* out = (float*)d_out;                // H (2*N*N) then F1(10), F2(10)

    int*   wsI = (int*)d_ws;
    int*   CNT = wsI + CNT_OFF;
    int*   WLC = wsI + WLC_OFF;
    int*   WL  = wsI + WL_OFF;
    unsigned long long* P8 = (unsigned long long*)(wsI + P8_OFF);
    int2*  A4  = (int2*)(wsI + A4_OFF);
    float* F   = (float*)(wsI + F_OFF);

    float* out_tail = out + (size_t)NCH * N * N;
    init_kernel<<<33, 256, 0, stream>>>(w1, w2, F, out_tail, CNT);

    int total_edges = NREL * NEDGE;
    scatter_csr<<<(total_edges + 255) / 256, 256, 0, stream>>>(ei, ev, F, CNT, P8, A4);

    spgemm_approx<<<dim3(N, 2), 256, 0, stream>>>(CNT, P8, A4, out, WLC, WL);
    spgemm_exact<<<WLCAP, 256, 0, stream>>>(CNT, P8, A4, out, WLC, WL);
}

// Round 12
// 155.557 us; speedup vs baseline: 1.5755x; 1.0166x over previous
//
#include <hip/hip_runtime.h>
#include <math.h>

#define N 4096
#define NREL 5
#define NCH 2
#define NEDGE 131072
#define THRESH 0.05f
#define FSCALE 268435456.0f          // 2^28 fixed point for adjacency entries
#define INV_P24F (1.0f/16777216.0f)  // 2^-24 (exact)
#define INV_P56 (1.0/72057594037927936.0)   // 2^-56 (double, exact)
#define ROWCAP 192                   // per (row, col-half) capacity: Poisson(80), +12.5 sigma
#define KCAP   320                   // klist capacity (full row): Poisson(160), +12.7 sigma

#define THRQ24  838860               // floor(0.05f * 2^24); cut acc > THRQ24 == x > 0.05f
#define MARGIN24 16                  // covers n<=32 products x 0.5 ulp; P(n>32)~1e-16/cell
#define OVERQ24 33554432u            // 2.0 * 2^24 per half -> exact recompute (wrap at 256)
#define WLCAP   16384                // = N*2*2 = ALL (m,h,c) blocks: drops impossible
#define Q2MASK  0x3FFFFFFu

// ws layout in 4-byte elements:
//   CNT [0, 2N)          per (row, half) counts (shared structure)
//   WLC [2N]             worklist counter
//   WL  [2N+1, +WLCAP)   flagged (m<<2 | h<<1 | c); capacity = all blocks
//   P8  [P8_OFF ...)     packed 8B entries: col | q2a<<11 | q2b<<38 (RAW 2^-28 ints)
//   A4  [A4_OFF ...)     int2 (q1a, q1b) raw 2^-28 ints, parallel ordering
//   F   [F_OFF, +20)     softmax weights
#define CNT_OFF  ((size_t)0)
#define WLC_OFF  ((size_t)(2 * N))
#define WL_OFF   ((size_t)(2 * N + 1))
#define P8_OFF   ((size_t)32768)                     // past WL end (24577), 128KB-aligned
#define NENT     ((size_t)N * 2 * ROWCAP)            // 1,572,864 entries
#define A4_OFF   (P8_OFF + NENT * 2)
#define F_OFF    (A4_OFF + NENT * 2)

// Fused: zero CNT+WLC (blocks 0..31) and compute softmaxes (block 32).
__global__ void init_kernel(const float* __restrict__ w1,
                            const float* __restrict__ w2,
                            float* __restrict__ F,
                            float* __restrict__ out_tail,
                            int* __restrict__ CNTZ) {
    int gid = blockIdx.x * 256 + threadIdx.x;
    if (gid < 2 * N + 1) CNTZ[gid] = 0;
    if (blockIdx.x == 32 && threadIdx.x < 2 * NCH) {
        int c = threadIdx.x;
        const float* w = (c < NCH) ? w1 : w2;
        int row = c % NCH;
        int base = (c < NCH) ? 0 : NCH * NREL;
        float m = -1e30f;
        for (int r = 0; r < NREL; ++r) m = fmaxf(m, w[row * NREL + r]);
        float e[NREL];
        float s = 0.f;
        for (int r = 0; r < NREL; ++r) { e[r] = expf(w[row * NREL + r] - m); s += e[r]; }
        float inv = 1.0f / s;
        for (int r = 0; r < NREL; ++r) {
            float f = e[r] * inv;
            F[base + row * NREL + r] = f;
            out_tail[base + row * NREL + r] = f;
        }
    }
}

// Append edges to bucketed CSR. Duplicates unmerged (distributive integer
// accumulation == dense coalescing, bit-exact); entry order racy but all
// consumers are order-independent integer sums -> deterministic output.
__global__ void scatter_csr(const int* __restrict__ ei,
                            const float* __restrict__ ev,
                            const float* __restrict__ F,
                            int* __restrict__ CNT,
                            unsigned long long* __restrict__ P8,
                            int2* __restrict__ A4) {
    int t = blockIdx.x * blockDim.x + threadIdx.x;
    if (t >= NREL * NEDGE) return;
    int r = t / NEDGE;
    int e = t - r * NEDGE;
    int i = ei[(size_t)(r * 2 + 0) * NEDGE + e];
    int j = ei[(size_t)(r * 2 + 1) * NEDGE + e];
    float v = ev[(size_t)r * NEDGE + e];
    int h  = j >> 11;
    int jl = j & 2047;
    int pos = atomicAdd(&CNT[i * 2 + h], 1);
    if (pos < ROWCAP) {
        size_t idx = ((size_t)i * 2 + h) * ROWCAP + pos;
        // per-edge quantization identical to the proven round-1/3/5/7 kernels
        unsigned q1a = (unsigned)__float2int_rn(F[0 * NREL + r] * v * FSCALE);
        unsigned q1b = (unsigned)__float2int_rn(F[1 * NREL + r] * v * FSCALE);
        unsigned q2a = (unsigned)__float2int_rn(F[NCH * NREL + 0 * NREL + r] * v * FSCALE);
        unsigned q2b = (unsigned)__float2int_rn(F[NCH * NREL + 1 * NREL + r] * v * FSCALE);
        // q2 < 2^26 given F ~ 0.2, v < 1 (clamp = pure safety, never hit)
        q2a = min(q2a, Q2MASK);
        q2b = min(q2b, Q2MASK);
        P8[idx] = (unsigned long long)(unsigned)jl
                | ((unsigned long long)q2a << 11)
                | ((unsigned long long)q2b << 38);
        A4[idx] = make_int2((int)q1a, (int)q1b);
    }
}

// Pad each odd-count (row, half) with one zero entry so the approx pair loop
// is branch-free. Zero entries contribute exactly 0 (to acc[0]) through PROC.
__global__ void pad_kernel(const int* __restrict__ CNT,
                           unsigned long long* __restrict__ P8) {
    int idx = blockIdx.x * 256 + threadIdx.x;
    if (idx < 2 * N) {
        int cnt = CNT[idx];
        if (cnt < ROWCAP && (cnt & 1))
            P8[(size_t)idx * ROWCAP + cnt] = 0ULL;
    }
}

// Pass 1: both channels. Per entry: two v_mad_u64_u32(q1, q2, 2^31); the high
// 32 bits ARE the 2^-24-scale contributions (no shifts, no repack) -> one
// ds_add_u64 (c0 low word, c1 high word; no carry cross while each half < 2^32
// <=> H < 256; flagged at 2.0). One block per (m, h); 16 16-lane slots;
// branch-free pair loop (rows padded to even count with zero entries).
__launch_bounds__(256, 8)
__global__ void spgemm_approx(const int* __restrict__ CNT,
                              const unsigned long long* __restrict__ P8,
                              const int2* __restrict__ A4,
                              float* __restrict__ out,
                              int* __restrict__ WLC,
                              int* __restrict__ WL) {
    __shared__ unsigned long long acc[2048];   // 16KB: lo=c0, hi=c1
    __shared__ int2 kA[KCAP];                  // (q1_c0, q1_c1)
    __shared__ unsigned short kK[KCAP];        // k
    __shared__ unsigned char  kCt[KCAP];       // inner row count (<=192)
    __shared__ int blkflag;
    const int m = blockIdx.x;
    const int h = blockIdx.y;

    for (int i = threadIdx.x; i < 2048; i += 256) acc[i] = 0ULL;
    if (threadIdx.x == 0) blkflag = 0;

    int nk0 = min(CNT[m * 2 + 0], ROWCAP);
    int nk1 = min(CNT[m * 2 + 1], ROWCAP);
    int nk = min(nk0 + nk1, KCAP);
    for (int i = threadIdx.x; i < nk; i += 256) {
        int b  = (i >= nk0) ? 1 : 0;
        int ii = i - (b ? nk0 : 0);
        size_t idx = ((size_t)m * 2 + b) * ROWCAP + ii;
        int k = (int)(P8[idx] & 2047ULL) + (b << 11);
        kK[i]  = (unsigned short)k;
        kCt[i] = (unsigned char)min(CNT[k * 2 + h], ROWCAP);
        kA[i]  = A4[idx];
    }
    __syncthreads();

    const int slot = threadIdx.x >> 4;   // 16 slots
    const int lane = threadIdx.x & 15;   // 16 lanes

#define PROC(eu, a0, a1)                                                        \
    {                                                                           \
        unsigned col = (unsigned)(eu) & 2047u;                                  \
        unsigned qa  = (unsigned)((eu) >> 11) & Q2MASK;                         \
        unsigned qb  = (unsigned)((eu) >> 38);                                  \
        unsigned long long pA =                                                 \
            (unsigned long long)(unsigned)(a0) * qa + (1ULL << 31);             \
        unsigned long long pB =                                                 \
            (unsigned long long)(unsigned)(a1) * qb + (1ULL << 31);             \
        unsigned uA = (unsigned)(pA >> 32);                                     \
        unsigned uB = (unsigned)(pB >> 32);                                     \
        atomicAdd(&acc[col],                                                    \
                  (unsigned long long)uA | ((unsigned long long)uB << 32));     \
    }

    for (int ki = slot; ki < nk; ki += 16) {
        int cntA = kCt[ki];
        int2 aA = kA[ki];
        const ulonglong2* __restrict__ rowA =
            (const ulonglong2*)(P8 + ((size_t)kK[ki] * 2 + h) * ROWCAP);
        int PA = (cntA + 1) >> 1;            // rows padded: both halves valid
        for (int p = lane; p < PA; p += 16) {
            ulonglong2 e = rowA[p];
            PROC(e.x, aA.x, aA.y);
            PROC(e.y, aA.x, aA.y);
        }
    }
#undef PROC
    __syncthreads();

    // epilogue: unpack halves, convert (exact: lo < 2^24 at scale 2^-24),
    // threshold, store both channels; flag near-boundary / overflow cells.
    float* orow0 = out + (size_t)0 * N * N + (size_t)m * N + ((size_t)h << 11);
    float* orow1 = out + (size_t)1 * N * N + (size_t)m * N + ((size_t)h << 11);
    bool f0 = false, f1 = false;
    for (int t = threadIdx.x; t < 512; t += 256) {
        float4 h0, h1;
        float* p0 = (float*)&h0;
        float* p1 = (float*)&h1;
#pragma unroll
        for (int u = 0; u < 4; ++u) {
            unsigned long long v = acc[t * 4 + u];
            unsigned lo = (unsigned)v;
            unsigned hi = (unsigned)(v >> 32);
            int d0 = (int)lo - THRQ24;
            int d1 = (int)hi - THRQ24;
            f0 |= (d0 <= MARGIN24 && d0 >= -MARGIN24) || (lo >= OVERQ24);
            f1 |= (d1 <= MARGIN24 && d1 >= -MARGIN24) || (hi >= OVERQ24);
            float x0 = (float)lo * INV_P24F;
            float x1 = (float)hi * INV_P24F;
            p0[u] = ((int)lo > THRQ24) ? x0 : 0.f;
            p1[u] = ((int)hi > THRQ24) ? x1 : 0.f;
        }
        *(float4*)&orow0[t * 4] = h0;
        *(float4*)&orow1[t * 4] = h1;
    }
    if (f0) atomicOr(&blkflag, 1);
    if (f1) atomicOr(&blkflag, 2);
    __syncthreads();
    if (threadIdx.x == 0 && blkflag) {
        // WLCAP == total block count -> pos can never reach WLCAP: no drops.
        if (blkflag & 1) {
            int pos = atomicAdd(WLC, 1);
            if (pos < WLCAP) WL[pos] = (m << 2) | (h << 1) | 0;
        }
        if (blkflag & 2) {
            int pos = atomicAdd(WLC, 1);
            if (pos < WLCAP) WL[pos] = (m << 2) | (h << 1) | 1;
        }
    }
}

// Pass 2: exact u64 recompute of flagged (m, h, c). P8 carries the RAW 2^-28
// q2 ints -> products q1*q2 and the u64 sum are bit-identical to the proven
// round-5/7 exact math. Overwrites the approximate output.
__launch_bounds__(256, 8)
__global__ void spgemm_exact(const int* __restrict__ CNT,
                             const unsigned long long* __restrict__ P8,
                             const int2* __restrict__ A4,
                             float* __restrict__ out,
                             const int* __restrict__ WLC,
                             const int* __restrict__ WL) {
    int nwl = min(*WLC, WLCAP);
    if ((int)blockIdx.x >= nwl) return;
    int wl = WL[blockIdx.x];
    int m = wl >> 2;
    int h = (wl >> 1) & 1;
    int c = wl & 1;

    __shared__ unsigned long long acc[2048];   // 16KB exact int64
    __shared__ unsigned kAc[KCAP];
    __shared__ unsigned short kK[KCAP];
    __shared__ unsigned char  kCt[KCAP];

    for (int i = threadIdx.x; i < 2048; i += 256) acc[i] = 0ULL;

    int nk0 = min(CNT[m * 2 + 0], ROWCAP);
    int nk1 = min(CNT[m * 2 + 1], ROWCAP);
    int nk = min(nk0 + nk1, KCAP);
    for (int i = threadIdx.x; i < nk; i += 256) {
        int b  = (i >= nk0) ? 1 : 0;
        int ii = i - (b ? nk0 : 0);
        size_t idx = ((size_t)m * 2 + b) * ROWCAP + ii;
        int k = (int)(P8[idx] & 2047ULL) + (b << 11);
        kK[i]  = (unsigned short)k;
        kCt[i] = (unsigned char)min(CNT[k * 2 + h], ROWCAP);
        int2 a = A4[idx];
        kAc[i] = (unsigned)(c ? a.y : a.x);
    }
    __syncthreads();

    const int slot = threadIdx.x >> 4;
    const int lane = threadIdx.x & 15;
    const int shift = c ? 38 : 11;

    for (int ki = slot; ki < nk; ki += 16) {
        int cnt = kCt[ki];
        unsigned long long a = (unsigned long long)kAc[ki];
        const unsigned long long* __restrict__ row =
            P8 + ((size_t)kK[ki] * 2 + h) * ROWCAP;
        for (int p = lane; p < cnt; p += 16) {
            unsigned long long e = row[p];
            unsigned col = (unsigned)e & 2047u;
            unsigned q2 = (unsigned)(e >> shift) & Q2MASK;
            atomicAdd(&acc[col], a * (unsigned long long)q2);
        }
    }
    __syncthreads();

    float* orow = out + (size_t)c * N * N + (size_t)m * N + ((size_t)h << 11);
    for (int t = threadIdx.x; t < 512; t += 256) {
        float4 hv;
        float* hp = (float*)&hv;
#pragma unroll
        for (int u = 0; u < 4; ++u) {
            double d = (double)(long long)acc[t * 4 + u] * INV_P56;
            float f = (float)d;
            hp[u] = (f > THRESH) ? f : 0.f;
        }
        *(float4*)&orow[t * 4] = hv;
    }
}

extern "C" void kernel_launch(void* const* d_in, const int* in_sizes, int n_in,
                              void* d_out, int out_size, void* d_ws, size_t ws_size,
                              hipStream_t stream) {
    const int*   ei = (const int*)d_in[0];     // [5, 2, 131072]
    const float* ev = (const float*)d_in[1];   // [5, 131072]
    const float* w1 = (const float*)d_in[2];   // [2, 5]
    const float* w2 = (const float*)d_in[3];   // [2, 5]
    float* out = (float*)d_out;                // H (2*N*N) then F1(10), F2(10)

    int*   wsI = (int*)d_ws;
    int*   CNT = wsI + CNT_OFF;
    int*   WLC = wsI + WLC_OFF;
    int*   WL  = wsI + WL_OFF;
    unsigned long long* P8 = (unsigned long long*)(wsI + P8_OFF);
    int2*  A4  = (int2*)(wsI + A4_OFF);
    float* F   = (float*)(wsI + F_OFF);

    float* out_tail = out + (size_t)NCH * N * N;
    init_kernel<<<33, 256, 0, stream>>>(w1, w2, F, out_tail, CNT);

    int total_edges = NREL * NEDGE;
    scatter_csr<<<(total_edges + 255) / 256, 256, 0, stream>>>(ei, ev, F, CNT, P8, A4);

    pad_kernel<<<32, 256, 0, stream>>>(CNT, P8);

    spgemm_approx<<<dim3(N, 2), 256, 0, stream>>>(CNT, P8, A4, out, WLC, WL);
    spgemm_exact<<<WLCAP, 256, 0, stream>>>(CNT, P8, A4, out, WLC, WL);
}

// Round 13
// 143.919 us; speedup vs baseline: 1.7029x; 1.0809x over previous
//
#include <hip/hip_runtime.h>
#include <math.h>

#define N 4096
#define NREL 5
#define NCH 2
#define NEDGE 131072
#define THRESH 0.05f
#define FSCALE 268435456.0f          // 2^28 fixed point for adjacency entries
#define INV_P24F (1.0f/16777216.0f)  // 2^-24 (exact)
#define INV_P56 (1.0/72057594037927936.0)   // 2^-56 (double, exact)
#define ROWCAP 192                   // per (row, col-half) capacity: Poisson(80), +12.5 sigma; %4==0
#define KCAP   320                   // klist capacity (full row): Poisson(160), +12.7 sigma

#define THRQ24  838860               // floor(0.05f * 2^24); cut acc > THRQ24 == x > 0.05f
#define MARGIN24 16                  // covers n<=32 products x 0.5 ulp; P(n>32)~1e-16/cell
#define OVERQ24 33554432u            // 2.0 * 2^24 per half -> exact recompute (wrap at 256)
#define WLCAP   16384                // = N*2*2 = ALL (m,h,c) blocks: drops impossible
#define Q2MASK  0x3FFFFFFu

// ws layout in 4-byte elements:
//   CNT [0, 2N)          per (row, half) counts (shared structure)
//   WLC [2N]             worklist counter
//   WL  [2N+1, +WLCAP)   flagged (m<<2 | h<<1 | c); capacity = all blocks
//   P8  [P8_OFF ...)     packed 8B entries: col | q2a<<11 | q2b<<38 (RAW 2^-28 ints)
//   A4  [A4_OFF ...)     int2 (q1a, q1b) raw 2^-28 ints, parallel ordering
//   F   [F_OFF, +20)     softmax weights
#define CNT_OFF  ((size_t)0)
#define WLC_OFF  ((size_t)(2 * N))
#define WL_OFF   ((size_t)(2 * N + 1))
#define P8_OFF   ((size_t)32768)                     // past WL end (24577), 128KB-aligned
#define NENT     ((size_t)N * 2 * ROWCAP)            // 1,572,864 entries
#define A4_OFF   (P8_OFF + NENT * 2)
#define F_OFF    (A4_OFF + NENT * 2)

// Fused: zero CNT+WLC (blocks 0..31) and compute softmaxes (block 32).
__global__ void init_kernel(const float* __restrict__ w1,
                            const float* __restrict__ w2,
                            float* __restrict__ F,
                            float* __restrict__ out_tail,
                            int* __restrict__ CNTZ) {
    int gid = blockIdx.x * 256 + threadIdx.x;
    if (gid < 2 * N + 1) CNTZ[gid] = 0;
    if (blockIdx.x == 32 && threadIdx.x < 2 * NCH) {
        int c = threadIdx.x;
        const float* w = (c < NCH) ? w1 : w2;
        int row = c % NCH;
        int base = (c < NCH) ? 0 : NCH * NREL;
        float m = -1e30f;
        for (int r = 0; r < NREL; ++r) m = fmaxf(m, w[row * NREL + r]);
        float e[NREL];
        float s = 0.f;
        for (int r = 0; r < NREL; ++r) { e[r] = expf(w[row * NREL + r] - m); s += e[r]; }
        float inv = 1.0f / s;
        for (int r = 0; r < NREL; ++r) {
            float f = e[r] * inv;
            F[base + row * NREL + r] = f;
            out_tail[base + row * NREL + r] = f;
        }
    }
}

// Append edges to bucketed CSR. Duplicates unmerged (distributive integer
// accumulation == dense coalescing, bit-exact); entry order racy but all
// consumers are order-independent integer sums -> deterministic output.
__global__ void scatter_csr(const int* __restrict__ ei,
                            const float* __restrict__ ev,
                            const float* __restrict__ F,
                            int* __restrict__ CNT,
                            unsigned long long* __restrict__ P8,
                            int2* __restrict__ A4) {
    int t = blockIdx.x * blockDim.x + threadIdx.x;
    if (t >= NREL * NEDGE) return;
    int r = t / NEDGE;
    int e = t - r * NEDGE;
    int i = ei[(size_t)(r * 2 + 0) * NEDGE + e];
    int j = ei[(size_t)(r * 2 + 1) * NEDGE + e];
    float v = ev[(size_t)r * NEDGE + e];
    int h  = j >> 11;
    int jl = j & 2047;
    int pos = atomicAdd(&CNT[i * 2 + h], 1);
    if (pos < ROWCAP) {
        size_t idx = ((size_t)i * 2 + h) * ROWCAP + pos;
        // per-edge quantization identical to the proven round-1/3/5/7 kernels
        unsigned q1a = (unsigned)__float2int_rn(F[0 * NREL + r] * v * FSCALE);
        unsigned q1b = (unsigned)__float2int_rn(F[1 * NREL + r] * v * FSCALE);
        unsigned q2a = (unsigned)__float2int_rn(F[NCH * NREL + 0 * NREL + r] * v * FSCALE);
        unsigned q2b = (unsigned)__float2int_rn(F[NCH * NREL + 1 * NREL + r] * v * FSCALE);
        // q2 < 2^26 given F ~ 0.2, v < 1 (clamp = pure safety, never hit)
        q2a = min(q2a, Q2MASK);
        q2b = min(q2b, Q2MASK);
        P8[idx] = (unsigned long long)(unsigned)jl
                | ((unsigned long long)q2a << 11)
                | ((unsigned long long)q2b << 38);
        A4[idx] = make_int2((int)q1a, (int)q1b);
    }
}

// Pad each (row, half) up to a multiple of 4 entries with zeros so the approx
// quad loop is branch-free. Zero entries contribute exactly 0 (to acc[0]).
__global__ void pad_kernel(const int* __restrict__ CNT,
                           unsigned long long* __restrict__ P8) {
    int idx = blockIdx.x * 256 + threadIdx.x;
    if (idx < 2 * N) {
        int cnt = min(CNT[idx], ROWCAP);
        int end = min((cnt + 3) & ~3, ROWCAP);
        for (int p = cnt; p < end; ++p)
            P8[(size_t)idx * ROWCAP + p] = 0ULL;
    }
}

// Pass 1: both channels. Per entry: two v_mad_u64_u32(q1, q2, 2^31); the high
// 32 bits ARE the 2^-24-scale contributions -> one ds_add_u64 (c0 low word,
// c1 high word; no carry cross while each half < 2^32 <=> H < 256; flagged at
// 2.0). One block per (m, h); 32 slots x 8 lanes (40 pairs / 8 lanes = ~99%
// mean lane utilization); quad-unrolled branch-free loop (rows padded to 4).
__launch_bounds__(256, 8)
__global__ void spgemm_approx(const int* __restrict__ CNT,
                              const unsigned long long* __restrict__ P8,
                              const int2* __restrict__ A4,
                              float* __restrict__ out,
                              int* __restrict__ WLC,
                              int* __restrict__ WL) {
    __shared__ unsigned long long acc[2048];   // 16KB: lo=c0, hi=c1
    __shared__ int2 kA[KCAP];                  // (q1_c0, q1_c1)
    __shared__ unsigned short kK[KCAP];        // k
    __shared__ unsigned char  kCt[KCAP];       // inner row count (<=192)
    __shared__ int blkflag;
    const int m = blockIdx.x;
    const int h = blockIdx.y;

    for (int i = threadIdx.x; i < 2048; i += 256) acc[i] = 0ULL;
    if (threadIdx.x == 0) blkflag = 0;

    int nk0 = min(CNT[m * 2 + 0], ROWCAP);
    int nk1 = min(CNT[m * 2 + 1], ROWCAP);
    int nk = min(nk0 + nk1, KCAP);
    for (int i = threadIdx.x; i < nk; i += 256) {
        int b  = (i >= nk0) ? 1 : 0;
        int ii = i - (b ? nk0 : 0);
        size_t idx = ((size_t)m * 2 + b) * ROWCAP + ii;
        int k = (int)(P8[idx] & 2047ULL) + (b << 11);
        kK[i]  = (unsigned short)k;
        kCt[i] = (unsigned char)min(CNT[k * 2 + h], ROWCAP);
        kA[i]  = A4[idx];
    }
    __syncthreads();

    const int slot = threadIdx.x >> 3;   // 32 slots
    const int lane = threadIdx.x & 7;    // 8 lanes

#define PROC(eu, a0, a1)                                                        \
    {                                                                           \
        unsigned col = (unsigned)(eu) & 2047u;                                  \
        unsigned qa  = (unsigned)((eu) >> 11) & Q2MASK;                         \
        unsigned qb  = (unsigned)((eu) >> 38);                                  \
        unsigned long long pA =                                                 \
            (unsigned long long)(unsigned)(a0) * qa + (1ULL << 31);             \
        unsigned long long pB =                                                 \
            (unsigned long long)(unsigned)(a1) * qb + (1ULL << 31);             \
        unsigned uA = (unsigned)(pA >> 32);                                     \
        unsigned uB = (unsigned)(pB >> 32);                                     \
        atomicAdd(&acc[col],                                                    \
                  (unsigned long long)uA | ((unsigned long long)uB << 32));     \
    }

    for (int ki = slot; ki < nk; ki += 32) {
        int cntA = kCt[ki];
        int2 aA = kA[ki];
        const ulonglong2* __restrict__ rowA =
            (const ulonglong2*)(P8 + ((size_t)kK[ki] * 2 + h) * ROWCAP);
        int QA = (cntA + 3) >> 2;            // quads; rows padded to 4-multiples
        for (int q = lane; q < QA; q += 8) {
            ulonglong2 e0 = rowA[2 * q];     // two independent 16B loads
            ulonglong2 e1 = rowA[2 * q + 1];
            PROC(e0.x, aA.x, aA.y);
            PROC(e0.y, aA.x, aA.y);
            PROC(e1.x, aA.x, aA.y);
            PROC(e1.y, aA.x, aA.y);
        }
    }
#undef PROC
    __syncthreads();

    // epilogue: unpack halves, convert (exact: lo < 2^24 at scale 2^-24),
    // threshold, store both channels; flag near-boundary / overflow cells.
    float* orow0 = out + (size_t)0 * N * N + (size_t)m * N + ((size_t)h << 11);
    float* orow1 = out + (size_t)1 * N * N + (size_t)m * N + ((size_t)h << 11);
    bool f0 = false, f1 = false;
    for (int t = threadIdx.x; t < 512; t += 256) {
        float4 h0, h1;
        float* p0 = (float*)&h0;
        float* p1 = (float*)&h1;
#pragma unroll
        for (int u = 0; u < 4; ++u) {
            unsigned long long v = acc[t * 4 + u];
            unsigned lo = (unsigned)v;
            unsigned hi = (unsigned)(v >> 32);
            int d0 = (int)lo - THRQ24;
            int d1 = (int)hi - THRQ24;
            f0 |= (d0 <= MARGIN24 && d0 >= -MARGIN24) || (lo >= OVERQ24);
            f1 |= (d1 <= MARGIN24 && d1 >= -MARGIN24) || (hi >= OVERQ24);
            float x0 = (float)lo * INV_P24F;
            float x1 = (float)hi * INV_P24F;
            p0[u] = ((int)lo > THRQ24) ? x0 : 0.f;
            p1[u] = ((int)hi > THRQ24) ? x1 : 0.f;
        }
        *(float4*)&orow0[t * 4] = h0;
        *(float4*)&orow1[t * 4] = h1;
    }
    if (f0) atomicOr(&blkflag, 1);
    if (f1) atomicOr(&blkflag, 2);
    __syncthreads();
    if (threadIdx.x == 0 && blkflag) {
        // WLCAP == total block count -> pos can never reach WLCAP: no drops.
        if (blkflag & 1) {
            int pos = atomicAdd(WLC, 1);
            if (pos < WLCAP) WL[pos] = (m << 2) | (h << 1) | 0;
        }
        if (blkflag & 2) {
            int pos = atomicAdd(WLC, 1);
            if (pos < WLCAP) WL[pos] = (m << 2) | (h << 1) | 1;
        }
    }
}

// Pass 2: exact u64 recompute of flagged (m, h, c). P8 carries the RAW 2^-28
// q2 ints -> products q1*q2 and the u64 sum are bit-identical to the proven
// round-5/7 exact math. Overwrites the approximate output. (Zero pad entries
// contribute 0 to acc[0]; col 0's value is computed identically regardless.)
__launch_bounds__(256, 8)
__global__ void spgemm_exact(const int* __restrict__ CNT,
                             const unsigned long long* __restrict__ P8,
                             const int2* __restrict__ A4,
                             float* __restrict__ out,
                             const int* __restrict__ WLC,
                             const int* __restrict__ WL) {
    int nwl = min(*WLC, WLCAP);
    if ((int)blockIdx.x >= nwl) return;
    int wl = WL[blockIdx.x];
    int m = wl >> 2;
    int h = (wl >> 1) & 1;
    int c = wl & 1;

    __shared__ unsigned long long acc[2048];   // 16KB exact int64
    __shared__ unsigned kAc[KCAP];
    __shared__ unsigned short kK[KCAP];
    __shared__ unsigned char  kCt[KCAP];

    for (int i = threadIdx.x; i < 2048; i += 256) acc[i] = 0ULL;

    int nk0 = min(CNT[m * 2 + 0], ROWCAP);
    int nk1 = min(CNT[m * 2 + 1], ROWCAP);
    int nk = min(nk0 + nk1, KCAP);
    for (int i = threadIdx.x; i < nk; i += 256) {
        int b  = (i >= nk0) ? 1 : 0;
        int ii = i - (b ? nk0 : 0);
        size_t idx = ((size_t)m * 2 + b) * ROWCAP + ii;
        int k = (int)(P8[idx] & 2047ULL) + (b << 11);
        kK[i]  = (unsigned short)k;
        kCt[i] = (unsigned char)min(CNT[k * 2 + h], ROWCAP);
        int2 a = A4[idx];
        kAc[i] = (unsigned)(c ? a.y : a.x);
    }
    __syncthreads();

    const int slot = threadIdx.x >> 4;
    const int lane = threadIdx.x & 15;
    const int shift = c ? 38 : 11;

    for (int ki = slot; ki < nk; ki += 16) {
        int cnt = kCt[ki];
        unsigned long long a = (unsigned long long)kAc[ki];
        const unsigned long long* __restrict__ row =
            P8 + ((size_t)kK[ki] * 2 + h) * ROWCAP;
        for (int p = lane; p < cnt; p += 16) {
            unsigned long long e = row[p];
            unsigned col = (unsigned)e & 2047u;
            unsigned q2 = (unsigned)(e >> shift) & Q2MASK;
            atomicAdd(&acc[col], a * (unsigned long long)q2);
        }
    }
    __syncthreads();

    float* orow = out + (size_t)c * N * N + (size_t)m * N + ((size_t)h << 11);
    for (int t = threadIdx.x; t < 512; t += 256) {
        float4 hv;
        float* hp = (float*)&hv;
#pragma unroll
        for (int u = 0; u < 4; ++u) {
            double d = (double)(long long)acc[t * 4 + u] * INV_P56;
            float f = (float)d;
            hp[u] = (f > THRESH) ? f : 0.f;
        }
        *(float4*)&orow[t * 4] = hv;
    }
}

extern "C" void kernel_launch(void* const* d_in, const int* in_sizes, int n_in,
                              void* d_out, int out_size, void* d_ws, size_t ws_size,
                              hipStream_t stream) {
    const int*   ei = (const int*)d_in[0];     // [5, 2, 131072]
    const float* ev = (const float*)d_in[1];   // [5, 131072]
    const float* w1 = (const float*)d_in[2];   // [2, 5]
    const float* w2 = (const float*)d_in[3];   // [2, 5]
    float* out = (float*)d_out;                // H (2*N*N) then F1(10), F2(10)

    int*   wsI = (int*)d_ws;
    int*   CNT = wsI + CNT_OFF;
    int*   WLC = wsI + WLC_OFF;
    int*   WL  = wsI + WL_OFF;
    unsigned long long* P8 = (unsigned long long*)(wsI + P8_OFF);
    int2*  A4  = (int2*)(wsI + A4_OFF);
    float* F   = (float*)(wsI + F_OFF);

    float* out_tail = out + (size_t)NCH * N * N;
    init_kernel<<<33, 256, 0, stream>>>(w1, w2, F, out_tail, CNT);

    int total_edges = NREL * NEDGE;
    scatter_csr<<<(total_edges + 255) / 256, 256, 0, stream>>>(ei, ev, F, CNT, P8, A4);

    pad_kernel<<<32, 256, 0, stream>>>(CNT, P8);

    spgemm_approx<<<dim3(N, 2), 256, 0, stream>>>(CNT, P8, A4, out, WLC, WL);
    spgemm_exact<<<WLCAP, 256, 0, stream>>>(CNT, P8, A4, out, WLC, WL);
}

// Round 14
// 141.638 us; speedup vs baseline: 1.7303x; 1.0161x over previous
//
#include <hip/hip_runtime.h>
#include <math.h>

#define N 4096
#define NREL 5
#define NCH 2
#define NEDGE 131072
#define THRESH 0.05f
#define FSCALE 268435456.0f          // 2^28 fixed point for adjacency entries
#define INV_P24F (1.0f/16777216.0f)  // 2^-24 (exact)
#define INV_P56 (1.0/72057594037927936.0)   // 2^-56 (double, exact)
#define ROWCAP 192                   // per (row, col-half) capacity: Poisson(80), +12.5 sigma; %4==0
#define KCAP   320                   // klist capacity (full row): Poisson(160), +12.7 sigma

#define THRQ24  838860               // floor(0.05f * 2^24); cut acc > THRQ24 == x > 0.05f
#define MARGIN24 16                  // covers n<=32 products x 0.5 ulp; P(n>32)~1e-16/cell
#define OVERQ24 33554432u            // 2.0 * 2^24 per half -> exact recompute (wrap at 256)
#define WLCAP   16384                // = N*2*2 = ALL (m,h,c) blocks: drops impossible
#define Q2MASK  0x3FFFFFFu

// ws layout in 4-byte elements:
//   CNT [0, 2N)          per (row, half) counts (shared structure)
//   WLC [2N]             worklist counter
//   WL  [2N+1, +WLCAP)   flagged (m<<2 | h<<1 | c); capacity = all blocks
//   P8  [P8_OFF ...)     packed 8B entries: col | q2a<<11 | q2b<<38 (RAW 2^-28 ints)
//   A4  [A4_OFF ...)     int2 (q1a, q1b) raw 2^-28 ints, parallel ordering
//   F   [F_OFF, +20)     softmax weights
#define CNT_OFF  ((size_t)0)
#define WLC_OFF  ((size_t)(2 * N))
#define WL_OFF   ((size_t)(2 * N + 1))
#define P8_OFF   ((size_t)32768)                     // past WL end (24577), 128KB-aligned
#define NENT     ((size_t)N * 2 * ROWCAP)            // 1,572,864 entries
#define A4_OFF   (P8_OFF + NENT * 2)
#define F_OFF    (A4_OFF + NENT * 2)

// Fused: zero CNT+WLC (blocks 0..31) and compute softmaxes (block 32).
__global__ void init_kernel(const float* __restrict__ w1,
                            const float* __restrict__ w2,
                            float* __restrict__ F,
                            float* __restrict__ out_tail,
                            int* __restrict__ CNTZ) {
    int gid = blockIdx.x * 256 + threadIdx.x;
    if (gid < 2 * N + 1) CNTZ[gid] = 0;
    if (blockIdx.x == 32 && threadIdx.x < 2 * NCH) {
        int c = threadIdx.x;
        const float* w = (c < NCH) ? w1 : w2;
        int row = c % NCH;
        int base = (c < NCH) ? 0 : NCH * NREL;
        float m = -1e30f;
        for (int r = 0; r < NREL; ++r) m = fmaxf(m, w[row * NREL + r]);
        float e[NREL];
        float s = 0.f;
        for (int r = 0; r < NREL; ++r) { e[r] = expf(w[row * NREL + r] - m); s += e[r]; }
        float inv = 1.0f / s;
        for (int r = 0; r < NREL; ++r) {
            float f = e[r] * inv;
            F[base + row * NREL + r] = f;
            out_tail[base + row * NREL + r] = f;
        }
    }
}

// Append edges to bucketed CSR. Duplicates unmerged (distributive integer
// accumulation == dense coalescing, bit-exact); entry order racy but all
// consumers are order-independent integer sums -> deterministic output.
__global__ void scatter_csr(const int* __restrict__ ei,
                            const float* __restrict__ ev,
                            const float* __restrict__ F,
                            int* __restrict__ CNT,
                            unsigned long long* __restrict__ P8,
                            int2* __restrict__ A4) {
    int t = blockIdx.x * blockDim.x + threadIdx.x;
    if (t >= NREL * NEDGE) return;
    int r = t / NEDGE;
    int e = t - r * NEDGE;
    int i = ei[(size_t)(r * 2 + 0) * NEDGE + e];
    int j = ei[(size_t)(r * 2 + 1) * NEDGE + e];
    float v = ev[(size_t)r * NEDGE + e];
    int h  = j >> 11;
    int jl = j & 2047;
    int pos = atomicAdd(&CNT[i * 2 + h], 1);
    if (pos < ROWCAP) {
        size_t idx = ((size_t)i * 2 + h) * ROWCAP + pos;
        // per-edge quantization identical to the proven round-1/3/5/7 kernels
        unsigned q1a = (unsigned)__float2int_rn(F[0 * NREL + r] * v * FSCALE);
        unsigned q1b = (unsigned)__float2int_rn(F[1 * NREL + r] * v * FSCALE);
        unsigned q2a = (unsigned)__float2int_rn(F[NCH * NREL + 0 * NREL + r] * v * FSCALE);
        unsigned q2b = (unsigned)__float2int_rn(F[NCH * NREL + 1 * NREL + r] * v * FSCALE);
        // q2 < 2^26 given F ~ 0.2, v < 1 (clamp = pure safety, never hit)
        q2a = min(q2a, Q2MASK);
        q2b = min(q2b, Q2MASK);
        P8[idx] = (unsigned long long)(unsigned)jl
                | ((unsigned long long)q2a << 11)
                | ((unsigned long long)q2b << 38);
        A4[idx] = make_int2((int)q1a, (int)q1b);
    }
}

// Pad each (row, half) up to a multiple of 4 entries with zeros so the approx
// quad loop is branch-free. Zero entries contribute exactly 0 (to acc[0]).
__global__ void pad_kernel(const int* __restrict__ CNT,
                           unsigned long long* __restrict__ P8) {
    int idx = blockIdx.x * 256 + threadIdx.x;
    if (idx < 2 * N) {
        int cnt = min(CNT[idx], ROWCAP);
        int end = min((cnt + 3) & ~3, ROWCAP);
        for (int p = cnt; p < end; ++p)
            P8[(size_t)idx * ROWCAP + p] = 0ULL;
    }
}

// Pass 1: both channels. Per entry: two v_mad_u64_u32(q1, q2, 2^31); the high
// 32 bits ARE the 2^-24-scale contributions -> one ds_add_u64 (c0 low word,
// c1 high word; no carry cross while each half < 2^32 <=> H < 256; flagged at
// 2.0). One block per (m, h); 32 slots x 8 lanes; kCt carries QUAD count;
// quad-unrolled branch-free loop (rows padded to 4-multiples).
__launch_bounds__(256, 8)
__global__ void spgemm_approx(const int* __restrict__ CNT,
                              const unsigned long long* __restrict__ P8,
                              const int2* __restrict__ A4,
                              float* __restrict__ out,
                              int* __restrict__ WLC,
                              int* __restrict__ WL) {
    __shared__ unsigned long long acc[2048];   // 16KB: lo=c0, hi=c1
    __shared__ int2 kA[KCAP];                  // (q1_c0, q1_c1)
    __shared__ unsigned short kK[KCAP];        // k
    __shared__ unsigned char  kCt[KCAP];       // inner row QUAD count (<=48)
    __shared__ int blkflag;
    const int m = blockIdx.x;
    const int h = blockIdx.y;

    for (int i = threadIdx.x; i < 2048; i += 256) acc[i] = 0ULL;
    if (threadIdx.x == 0) blkflag = 0;

    int nk0 = min(CNT[m * 2 + 0], ROWCAP);
    int nk1 = min(CNT[m * 2 + 1], ROWCAP);
    int nk = min(nk0 + nk1, KCAP);
    for (int i = threadIdx.x; i < nk; i += 256) {
        int b  = (i >= nk0) ? 1 : 0;
        int ii = i - (b ? nk0 : 0);
        size_t idx = ((size_t)m * 2 + b) * ROWCAP + ii;
        int k = (int)(P8[idx] & 2047ULL) + (b << 11);
        kK[i]  = (unsigned short)k;
        kCt[i] = (unsigned char)((min(CNT[k * 2 + h], ROWCAP) + 3) >> 2);
        kA[i]  = A4[idx];
    }
    __syncthreads();

    const int slot = threadIdx.x >> 3;   // 32 slots
    const int lane = threadIdx.x & 7;    // 8 lanes

#define PROC(eu, a0, a1)                                                        \
    {                                                                           \
        unsigned col = (unsigned)(eu) & 2047u;                                  \
        unsigned qa  = (unsigned)((eu) >> 11) & Q2MASK;                         \
        unsigned qb  = (unsigned)((eu) >> 38);                                  \
        unsigned long long pA =                                                 \
            (unsigned long long)(unsigned)(a0) * qa + (1ULL << 31);             \
        unsigned long long pB =                                                 \
            (unsigned long long)(unsigned)(a1) * qb + (1ULL << 31);             \
        unsigned uA = (unsigned)(pA >> 32);                                     \
        unsigned uB = (unsigned)(pB >> 32);                                     \
        atomicAdd(&acc[col],                                                    \
                  (unsigned long long)uA | ((unsigned long long)uB << 32));     \
    }

    for (int ki = slot; ki < nk; ki += 32) {
        int QA = kCt[ki];                    // quad count (rows padded to 4)
        int2 aA = kA[ki];
        const ulonglong2* __restrict__ rowA =
            (const ulonglong2*)(P8 + ((size_t)kK[ki] * 2 + h) * ROWCAP);
        for (int q = lane; q < QA; q += 8) {
            ulonglong2 e0 = rowA[2 * q];     // two independent 16B loads
            ulonglong2 e1 = rowA[2 * q + 1];
            PROC(e0.x, aA.x, aA.y);
            PROC(e0.y, aA.x, aA.y);
            PROC(e1.x, aA.x, aA.y);
            PROC(e1.y, aA.x, aA.y);
        }
    }
#undef PROC
    __syncthreads();

    // epilogue: unpack halves, convert (exact: lo < 2^24 at scale 2^-24),
    // threshold, store both channels; flag near-boundary / overflow cells.
    float* orow0 = out + (size_t)0 * N * N + (size_t)m * N + ((size_t)h << 11);
    float* orow1 = out + (size_t)1 * N * N + (size_t)m * N + ((size_t)h << 11);
    bool f0 = false, f1 = false;
    for (int t = threadIdx.x; t < 512; t += 256) {
        float4 h0, h1;
        float* p0 = (float*)&h0;
        float* p1 = (float*)&h1;
#pragma unroll
        for (int u = 0; u < 4; ++u) {
            unsigned long long v = acc[t * 4 + u];
            unsigned lo = (unsigned)v;
            unsigned hi = (unsigned)(v >> 32);
            int d0 = (int)lo - THRQ24;
            int d1 = (int)hi - THRQ24;
            f0 |= (d0 <= MARGIN24 && d0 >= -MARGIN24) || (lo >= OVERQ24);
            f1 |= (d1 <= MARGIN24 && d1 >= -MARGIN24) || (hi >= OVERQ24);
            float x0 = (float)lo * INV_P24F;
            float x1 = (float)hi * INV_P24F;
            p0[u] = ((int)lo > THRQ24) ? x0 : 0.f;
            p1[u] = ((int)hi > THRQ24) ? x1 : 0.f;
        }
        *(float4*)&orow0[t * 4] = h0;
        *(float4*)&orow1[t * 4] = h1;
    }
    if (f0) atomicOr(&blkflag, 1);
    if (f1) atomicOr(&blkflag, 2);
    __syncthreads();
    if (threadIdx.x == 0 && blkflag) {
        // WLCAP == total block count -> pos can never reach WLCAP: no drops.
        if (blkflag & 1) {
            int pos = atomicAdd(WLC, 1);
            if (pos < WLCAP) WL[pos] = (m << 2) | (h << 1) | 0;
        }
        if (blkflag & 2) {
            int pos = atomicAdd(WLC, 1);
            if (pos < WLCAP) WL[pos] = (m << 2) | (h << 1) | 1;
        }
    }
}

// Pass 2: exact u64 recompute of flagged (m, h, c). P8 carries the RAW 2^-28
// q2 ints -> products q1*q2 and the u64 sum are bit-identical to the proven
// round-5/7 exact math. Pad zeros contribute 0 (to acc[0]) — harmless. 8-lane
// slots matching approx geometry. Overwrites the approximate output.
__launch_bounds__(256, 8)
__global__ void spgemm_exact(const int* __restrict__ CNT,
                             const unsigned long long* __restrict__ P8,
                             const int2* __restrict__ A4,
                             float* __restrict__ out,
                             const int* __restrict__ WLC,
                             const int* __restrict__ WL) {
    int nwl = min(*WLC, WLCAP);
    if ((int)blockIdx.x >= nwl) return;
    int wl = WL[blockIdx.x];
    int m = wl >> 2;
    int h = (wl >> 1) & 1;
    int c = wl & 1;

    __shared__ unsigned long long acc[2048];   // 16KB exact int64
    __shared__ unsigned kAc[KCAP];
    __shared__ unsigned short kK[KCAP];
    __shared__ unsigned char  kCt[KCAP];       // QUAD count

    for (int i = threadIdx.x; i < 2048; i += 256) acc[i] = 0ULL;

    int nk0 = min(CNT[m * 2 + 0], ROWCAP);
    int nk1 = min(CNT[m * 2 + 1], ROWCAP);
    int nk = min(nk0 + nk1, KCAP);
    for (int i = threadIdx.x; i < nk; i += 256) {
        int b  = (i >= nk0) ? 1 : 0;
        int ii = i - (b ? nk0 : 0);
        size_t idx = ((size_t)m * 2 + b) * ROWCAP + ii;
        int k = (int)(P8[idx] & 2047ULL) + (b << 11);
        kK[i]  = (unsigned short)k;
        kCt[i] = (unsigned char)((min(CNT[k * 2 + h], ROWCAP) + 3) >> 2);
        int2 a = A4[idx];
        kAc[i] = (unsigned)(c ? a.y : a.x);
    }
    __syncthreads();

    const int slot = threadIdx.x >> 3;   // 32 slots
    const int lane = threadIdx.x & 7;    // 8 lanes
    const int shift = c ? 38 : 11;

    for (int ki = slot; ki < nk; ki += 32) {
        int cnt4 = (int)kCt[ki] << 2;        // padded entry count
        unsigned long long a = (unsigned long long)kAc[ki];
        const unsigned long long* __restrict__ row =
            P8 + ((size_t)kK[ki] * 2 + h) * ROWCAP;
        for (int p = lane; p < cnt4; p += 8) {
            unsigned long long e = row[p];
            unsigned col = (unsigned)e & 2047u;
            unsigned q2 = (unsigned)(e >> shift) & Q2MASK;
            atomicAdd(&acc[col], a * (unsigned long long)q2);
        }
    }
    __syncthreads();

    float* orow = out + (size_t)c * N * N + (size_t)m * N + ((size_t)h << 11);
    for (int t = threadIdx.x; t < 512; t += 256) {
        float4 hv;
        float* hp = (float*)&hv;
#pragma unroll
        for (int u = 0; u < 4; ++u) {
            double d = (double)(long long)acc[t * 4 + u] * INV_P56;
            float f = (float)d;
            hp[u] = (f > THRESH) ? f : 0.f;
        }
        *(float4*)&orow[t * 4] = hv;
    }
}

extern "C" void kernel_launch(void* const* d_in, const int* in_sizes, int n_in,
                              void* d_out, int out_size, void* d_ws, size_t ws_size,
                              hipStream_t stream) {
    const int*   ei = (const int*)d_in[0];     // [5, 2, 131072]
    const float* ev = (const float*)d_in[1];   // [5, 131072]
    const float* w1 = (const float*)d_in[2];   // [2, 5]
    const float* w2 = (const float*)d_in[3];   // [2, 5]
    float* out = (float*)d_out;                // H (2*N*N) then F1(10), F2(10)

    int*   wsI = (int*)d_ws;
    int*   CNT = wsI + CNT_OFF;
    int*   WLC = wsI + WLC_OFF;
    int*   WL  = wsI + WL_OFF;
    unsigned long long* P8 = (unsigned long long*)(wsI + P8_OFF);
    int2*  A4  = (int2*)(wsI + A4_OFF);
    float* F   = (float*)(wsI + F_OFF);

    float* out_tail = out + (size_t)NCH * N * N;
    init_kernel<<<33, 256, 0, stream>>>(w1, w2, F, out_tail, CNT);

    int total_edges = NREL * NEDGE;
    scatter_csr<<<(total_edges + 255) / 256, 256, 0, stream>>>(ei, ev, F, CNT, P8, A4);

    pad_kernel<<<32, 256, 0, stream>>>(CNT, P8);

    spgemm_approx<<<dim3(N, 2), 256, 0, stream>>>(CNT, P8, A4, out, WLC, WL);
    spgemm_exact<<<WLCAP, 256, 0, stream>>>(CNT, P8, A4, out, WLC, WL);
}